// Round 3
// baseline (2143.812 us; speedup 1.0000x reference)
//
#include <hip/hip_runtime.h>

#define N_NODES 131072
#define N_EDGES 524288
#define K_TOP   65536
#define LN_EPS  1e-5f

typedef unsigned int u32;
typedef unsigned short u16;
typedef unsigned long long u64;

// ---- ws layout (35MB total; small/critical at the bottom) ----
#define ST_OFF    0            // SelState (~18KB, reserve 64KB)
#define CANON_OFF (64u<<10)    // 115968 bf16 elems (~232KB, reserve to 1MB)
#define KEYS_OFF  (1u<<20)     // N u64 = 1MB
#define TVAL_OFF  (2u<<20)     // N f32 = 512KB
#define KEPT_OFF  ((2u<<20)+(512u<<10)) // N u32 = 512KB
#define A_OFF     (3u<<20)     // N x 64 u32 (bf16-pair accumulator) = 32MB
// d_out serves as S (proj bf16) -> R (recovered bf16) -> S2 -> final output.

// canonical parameter block offsets (bf16 elements)
#define C_DW1 0
#define C_DB1 16384
#define C_DW2 16512
#define C_DB2 32896
#define C_DW3 33024
#define C_DB3 49408
#define C_DG  49536
#define C_DBE 49664
#define C_UW1 49792
#define C_UB1 82560
#define C_UW2 82688
#define C_UB2 99072
#define C_UW3 99200
#define C_UB3 115584
#define C_UG  115712
#define C_UBE 115840
#define C_TOT 115968

__device__ __forceinline__ float bflo(u32 u){ return __uint_as_float(u << 16); }
__device__ __forceinline__ float bfhi(u32 u){ return __uint_as_float(u & 0xFFFF0000u); }
__device__ __forceinline__ float bf2f(u16 v){ return __uint_as_float(((u32)v) << 16); }
__device__ __forceinline__ u32 f2bf(float f){
  u32 u = __float_as_uint(f);
  return (u + 0x7FFFu + ((u >> 16) & 1u)) >> 16;
}
__device__ __forceinline__ float gelu_f(float x){
  return 0.5f * x * (1.0f + erff(x * 0.7071067811865476f));
}

struct SelState {
  u32 hist[256];
  u64 prefix;
  u32 krem, G, eqcnt;
  int is_f32;
  double inv_norm;
  u32 eqlist[4096];
};

struct P16 { const void* q[16]; };

// ---------------- dtype detection ----------------
// fp32 N(0,1) words: exponent field in [97,135] (|v| in [2^-30,2^8]) ~always.
// bf16-pair words: bits 23..30 come from the high bf16's low exponent+mantissa
// bits -> >=200 for N(0,1)-scale bf16 data. Clean separation.
__global__ void k_detect(const u32* __restrict__ xw, SelState* st){
  int t = threadIdx.x;  // 256
  int cnt = 0;
  for (int i = t; i < 4096; i += 256){
    u32 w = xw[(size_t)i * 2048];
    u32 e = (w >> 23) & 0xFFu;
    if (e >= 97u && e <= 135u) cnt++;
  }
  __shared__ int sh[256];
  sh[t] = cnt; __syncthreads();
  for (int o = 128; o > 0; o >>= 1){ if (t < o) sh[t] += sh[t+o]; __syncthreads(); }
  if (t == 0) st->is_f32 = (sh[0] >= 3072) ? 1 : 0;
}

__global__ void k_init(SelState* st){
  int t = threadIdx.x;
  if (t < 256) st->hist[t] = 0;
  if (t == 0){ st->prefix = 0; st->krem = K_TOP; st->G = 0; st->eqcnt = 0; }
}

// convert all 16 parameter arrays to canonical bf16
__global__ void k_canon(P16 ps, const SelState* __restrict__ st, u16* __restrict__ canon){
  const int off[17] = {C_DW1,C_DB1,C_DW2,C_DB2,C_DW3,C_DB3,C_DG,C_DBE,
                       C_UW1,C_UB1,C_UW2,C_UB2,C_UW3,C_UB3,C_UG,C_UBE,C_TOT};
  int i = blockIdx.x * 256 + threadIdx.x;
  if (i >= C_TOT) return;
  int seg = 0;
  #pragma unroll
  for (int s2 = 0; s2 < 16; s2++) if (i >= off[s2+1]) seg = s2 + 1;
  int j = i - off[seg];
  if (st->is_f32) canon[i] = (u16)f2bf(((const float*)ps.q[seg])[j]);
  else            canon[i] = ((const u16*)ps.q[seg])[j];
}

__global__ void k_pnorm(const void* __restrict__ p, SelState* st){
  int t = threadIdx.x;  // 128
  float pv = st->is_f32 ? ((const float*)p)[t] : bf2f(((const u16*)p)[t]);
  __shared__ double sh[128];
  sh[t] = (double)pv * (double)pv;
  __syncthreads();
  for (int o = 64; o > 0; o >>= 1){ if (t < o) sh[t] += sh[t+o]; __syncthreads(); }
  if (t == 0) st->inv_norm = 1.0 / sqrt(sh[0]);
}

// f64 dot on RAW data so the top-k SET matches the f64 np reference exactly
__global__ __launch_bounds__(256) void k_score(const void* __restrict__ xraw, const void* __restrict__ praw,
                        const SelState* __restrict__ st,
                        u64* __restrict__ keys, float* __restrict__ tval){
  int t = threadIdx.x, lane = t & 63, w = t >> 6;
  int n = blockIdx.x * 4 + w;
  double d;
  if (st->is_f32){
    const float* xf = (const float*)xraw + (size_t)n * 128;
    const float* pf = (const float*)praw;
    d = (double)xf[lane] * (double)pf[lane]
      + (double)xf[64 + lane] * (double)pf[64 + lane];
  } else {
    const u32* xw = (const u32*)xraw + (size_t)n * 64;
    const u32* pw = (const u32*)praw;
    u32 xx = xw[lane], pv = pw[lane];
    d = (double)bflo(xx) * (double)bflo(pv) + (double)bfhi(xx) * (double)bfhi(pv);
  }
  for (int o = 32; o > 0; o >>= 1) d += __shfl_down(d, o, 64);
  if (lane == 0){
    double sc = d * st->inv_norm;
    u64 u = (u64)__double_as_longlong(sc);
    u64 key = (u & 0x8000000000000000ULL) ? ~u : (u | 0x8000000000000000ULL);
    keys[n] = key;
    tval[n] = tanhf((float)sc);
  }
}

__global__ void k_radix_pass(const u64* __restrict__ keys, SelState* st, int shift){
  int n = blockIdx.x * blockDim.x + threadIdx.x;
  u64 key = keys[n];
  bool m = (shift == 56) || ((key >> (shift + 8)) == st->prefix);
  if (m) atomicAdd(&st->hist[(u32)((key >> shift) & 255)], 1u);
}

__global__ void k_radix_scan(SelState* st){
  u32 cum = 0; int chosen = 0;
  u32 krem = st->krem;
  for (int b = 255; b >= 0; b--){
    u32 c = st->hist[b];
    if (cum + c >= krem){ chosen = b; break; }
    cum += c;
  }
  st->prefix = (st->prefix << 8) | (u64)(u32)chosen;
  st->krem = krem - cum;
  st->G += cum;
  for (int i = 0; i < 256; i++) st->hist[i] = 0;
}

__global__ void k_mark(const u64* __restrict__ keys, SelState* st, u32* __restrict__ kept){
  int n = blockIdx.x * blockDim.x + threadIdx.x;
  u64 thr = st->prefix;
  u64 k = keys[n];
  kept[n] = (k > thr) ? 1u : 0u;
  if (k == thr){
    u32 i = atomicAdd(&st->eqcnt, 1u);
    if (i < 4096) st->eqlist[i] = (u32)n;
  }
}

__global__ void k_tie(SelState* st, u32* __restrict__ kept){
  u32 m = st->eqcnt; if (m > 4096) m = 4096;
  u32 r = st->krem;
  for (u32 i = threadIdx.x; i < m; i += blockDim.x){
    u32 idx = st->eqlist[i];
    u32 rank = 0;
    for (u32 j = 0; j < m; j++) rank += (st->eqlist[j] < idx) ? 1u : 0u;
    if (rank < r) kept[idx] = 1u;   // lowest indices first == lax.top_k tie-break
  }
}

// ---------------- projection GEMMs (bf16-packed LDS, fp32 acc) ----------------
// S[n] = bf16(x[n]*tval[n] @ dW1)
__global__ __launch_bounds__(256) void k_proj_down(
    const void* __restrict__ xraw, const float* __restrict__ tval,
    const u16* __restrict__ Wc, const SelState* __restrict__ st,
    u32* __restrict__ S)
{
  __shared__ u32 in_s[64 * 66];
  __shared__ u32 Wl[128 * 64];
  int t = threadIdx.x;
  int row0 = blockIdx.x * 64;
  const u32* W32 = (const u32*)Wc;
  #pragma unroll
  for (int i = 0; i < 32; i++) Wl[t + i * 256] = W32[t + i * 256];

  if (st->is_f32){
    const float* xf = (const float*)xraw + (size_t)row0 * 128;
    for (int i = t; i < 64 * 64; i += 256){
      int r = i >> 6, cp = i & 63;
      float tv = tval[row0 + r];
      float2 v = *(const float2*)(xf + (size_t)r * 128 + 2 * cp);
      in_s[r * 66 + cp] = f2bf(v.x * tv) | (f2bf(v.y * tv) << 16);
    }
  } else {
    const u32* xw = (const u32*)xraw + (size_t)row0 * 64;
    for (int i = t; i < 64 * 64; i += 256){
      int r = i >> 6, cp = i & 63;
      u32 u = xw[(size_t)r * 64 + cp];
      float tv = tval[row0 + r];
      in_s[r * 66 + cp] = f2bf(bflo(u) * tv) | (f2bf(bfhi(u) * tv) << 16);
    }
  }
  __syncthreads();

  int jg = t & 31, rg = t >> 5;
  const u32* inb = &in_s[rg * 8 * 66];
  float acc[8][4];
  #pragma unroll
  for (int i = 0; i < 8; i++){ acc[i][0]=0.f; acc[i][1]=0.f; acc[i][2]=0.f; acc[i][3]=0.f; }

  for (int k2 = 0; k2 < 64; k2++){
    u32 wa = Wl[(2*k2)*64 + jg*2],   wb = Wl[(2*k2)*64 + jg*2 + 1];
    u32 wc = Wl[(2*k2+1)*64 + jg*2], wd = Wl[(2*k2+1)*64 + jg*2 + 1];
    float a0=bflo(wa), a1=bfhi(wa), a2=bflo(wb), a3=bfhi(wb);
    float c0=bflo(wc), c1=bfhi(wc), c2=bflo(wd), c3=bfhi(wd);
    #pragma unroll
    for (int i = 0; i < 8; i++){
      u32 vw = inb[i*66 + k2];
      float v0 = bflo(vw), v1 = bfhi(vw);
      acc[i][0] += v0*a0 + v1*c0;
      acc[i][1] += v0*a1 + v1*c1;
      acc[i][2] += v0*a2 + v1*c2;
      acc[i][3] += v0*a3 + v1*c3;
    }
  }
  #pragma unroll
  for (int i = 0; i < 8; i++){
    size_t r = row0 + rg * 8 + i;
    S[r * 64 + jg * 2    ] = f2bf(acc[i][0]) | (f2bf(acc[i][1]) << 16);
    S[r * 64 + jg * 2 + 1] = f2bf(acc[i][2]) | (f2bf(acc[i][3]) << 16);
  }
}

// S2[n] = bf16(R[n] @ uW1[0:128,:] + x[n] @ uW1[128:256,:]); in-place on d_out (per-block rows)
__global__ __launch_bounds__(256) void k_proj_up(
    const u32* __restrict__ R, const void* __restrict__ xraw,
    const u16* __restrict__ Wc, const SelState* __restrict__ st,
    u32* __restrict__ S2)
{
  __shared__ u32 in_s[64 * 66];
  __shared__ u32 Wl[128 * 64];
  int t = threadIdx.x;
  int row0 = blockIdx.x * 64;
  int jg = t & 31, rg = t >> 5;

  float acc[8][4];
  #pragma unroll
  for (int i = 0; i < 8; i++){ acc[i][0]=0.f; acc[i][1]=0.f; acc[i][2]=0.f; acc[i][3]=0.f; }

  for (int ph = 0; ph < 2; ph++){
    const u32* W32 = (const u32*)Wc + (size_t)ph * 8192;
    #pragma unroll
    for (int i = 0; i < 32; i++) Wl[t + i * 256] = W32[t + i * 256];
    if (ph == 0){
      for (int i = t; i < 64 * 64; i += 256){
        int r = i >> 6, cp = i & 63;
        in_s[r * 66 + cp] = R[(size_t)(row0 + r) * 64 + cp];
      }
    } else if (st->is_f32){
      const float* xf = (const float*)xraw + (size_t)row0 * 128;
      for (int i = t; i < 64 * 64; i += 256){
        int r = i >> 6, cp = i & 63;
        float2 v = *(const float2*)(xf + (size_t)r * 128 + 2 * cp);
        in_s[r * 66 + cp] = f2bf(v.x) | (f2bf(v.y) << 16);
      }
    } else {
      const u32* xw = (const u32*)xraw + (size_t)row0 * 64;
      for (int i = t; i < 64 * 64; i += 256){
        int r = i >> 6, cp = i & 63;
        in_s[r * 66 + cp] = xw[(size_t)r * 64 + cp];
      }
    }
    __syncthreads();
    const u32* inb = &in_s[rg * 8 * 66];
    for (int k2 = 0; k2 < 64; k2++){
      u32 wa = Wl[(2*k2)*64 + jg*2],   wb = Wl[(2*k2)*64 + jg*2 + 1];
      u32 wc = Wl[(2*k2+1)*64 + jg*2], wd = Wl[(2*k2+1)*64 + jg*2 + 1];
      float a0=bflo(wa), a1=bfhi(wa), a2=bflo(wb), a3=bfhi(wb);
      float c0=bflo(wc), c1=bfhi(wc), c2=bflo(wd), c3=bfhi(wd);
      #pragma unroll
      for (int i = 0; i < 8; i++){
        u32 vw = inb[i*66 + k2];
        float v0 = bflo(vw), v1 = bfhi(vw);
        acc[i][0] += v0*a0 + v1*c0;
        acc[i][1] += v0*a1 + v1*c1;
        acc[i][2] += v0*a2 + v1*c2;
        acc[i][3] += v0*a3 + v1*c3;
      }
    }
    __syncthreads();
  }
  #pragma unroll
  for (int i = 0; i < 8; i++){
    size_t r = row0 + rg * 8 + i;
    S2[r * 64 + jg * 2    ] = f2bf(acc[i][0]) | (f2bf(acc[i][1]) << 16);
    S2[r * 64 + jg * 2 + 1] = f2bf(acc[i][2]) | (f2bf(acc[i][3]) << 16);
  }
}

// ---------------- scatter via bf16-pair CAS (32MB accumulator) ----------------
__device__ __forceinline__ void cas_add2(u32* addr, float m0, float m1){
  u32 old = *addr, assumed;
  do {
    assumed = old;
    u32 nv = f2bf(bflo(assumed) + m0) | (f2bf(bfhi(assumed) + m1) << 16);
    if (nv == assumed) break;
    old = atomicCAS(addr, assumed, nv);
  } while (old != assumed);
}

__global__ __launch_bounds__(256) void k_scatter_down(
    const int* __restrict__ se, const int* __restrict__ re,
    const u32* __restrict__ kept,
    const u32* __restrict__ S, u32* __restrict__ A)
{
  long long id = (long long)blockIdx.x * 256 + threadIdx.x;
  int e = (int)(id >> 6), q = (int)(id & 63);
  int s = se[e], r = re[e];
  if (kept[s] & kept[r]){
    u32 ms = S[(size_t)s * 64 + q];
    u32 mr = S[(size_t)r * 64 + q];
    cas_add2(&A[(size_t)r * 64 + q], bflo(ms), bfhi(ms));
    cas_add2(&A[(size_t)s * 64 + q], bflo(mr), bfhi(mr));
  }
}

__global__ __launch_bounds__(256) void k_scatter_up(
    const int* __restrict__ se, const int* __restrict__ re,
    const u32* __restrict__ S, u32* __restrict__ A)
{
  long long id = (long long)blockIdx.x * 256 + threadIdx.x;
  int e = (int)(id >> 6), q = (int)(id & 63);
  int s = se[e], r = re[e];
  u32 ms = S[(size_t)s * 64 + q];
  u32 mr = S[(size_t)r * 64 + q];
  cas_add2(&A[(size_t)r * 64 + q], bflo(ms), bfhi(ms));
  cas_add2(&A[(size_t)s * 64 + q], bflo(mr), bfhi(mr));
}

// ---------------- fused MLP tail: gelu(agg+b1) -> @W2 gelu -> @W3 -> LN ----------------
// IS_DOWN=1: write recovered bf16 (0 for non-kept) to Rout. IS_DOWN=0: final store (dtype branch).
template<int IS_DOWN>
__global__ __launch_bounds__(256) void k_mlp(
    const u32* __restrict__ A,
    const u16* __restrict__ cb1, const u16* __restrict__ cW2, const u16* __restrict__ cb2,
    const u16* __restrict__ cW3, const u16* __restrict__ cb3,
    const u16* __restrict__ cg, const u16* __restrict__ cbe,
    const u32* __restrict__ kept, const SelState* __restrict__ st,
    u32* __restrict__ Rout, void* __restrict__ fout)
{
  __shared__ float in_s[16 * 132];
  __shared__ float h_s[16 * 132];
  __shared__ u32 Wl[128 * 64];
  __shared__ float sh_mu[16], sh_rs[16];
  int t = threadIdx.x;
  int row0 = blockIdx.x * 16;

  for (int i = t; i < 16 * 64; i += 256){
    int r = i >> 6, q = i & 63;
    u32 w = A[(size_t)(row0 + r) * 64 + q];
    in_s[r * 132 + 2*q    ] = gelu_f(bflo(w) + bf2f(cb1[2*q    ]));
    in_s[r * 132 + 2*q + 1] = gelu_f(bfhi(w) + bf2f(cb1[2*q + 1]));
  }
  const u32* W2w = (const u32*)cW2;
  #pragma unroll
  for (int i = 0; i < 32; i++) Wl[t + i * 256] = W2w[t + i * 256];
  __syncthreads();

  int jg = t & 31, rg = t >> 5, j0 = jg * 4;   // rg: 0..7, 2 rows each

  { // layer 2
    const float* inb = &in_s[rg * 2 * 132];
    float acc[2][4];
    #pragma unroll
    for (int i = 0; i < 2; i++){ acc[i][0]=0.f; acc[i][1]=0.f; acc[i][2]=0.f; acc[i][3]=0.f; }
    for (int k = 0; k < 128; k++){
      u32 w0 = Wl[k * 64 + jg * 2], w1 = Wl[k * 64 + jg * 2 + 1];
      float f0=bflo(w0), f1=bfhi(w0), f2=bflo(w1), f3=bfhi(w1);
      #pragma unroll
      for (int i = 0; i < 2; i++){
        float v = inb[i * 132 + k];
        acc[i][0] += v*f0; acc[i][1] += v*f1; acc[i][2] += v*f2; acc[i][3] += v*f3;
      }
    }
    float b0 = bf2f(cb2[j0]), b1 = bf2f(cb2[j0+1]), b2 = bf2f(cb2[j0+2]), b3 = bf2f(cb2[j0+3]);
    #pragma unroll
    for (int i = 0; i < 2; i++){
      float* hp = &h_s[(rg * 2 + i) * 132 + j0];
      hp[0] = gelu_f(acc[i][0] + b0); hp[1] = gelu_f(acc[i][1] + b1);
      hp[2] = gelu_f(acc[i][2] + b2); hp[3] = gelu_f(acc[i][3] + b3);
    }
  }
  __syncthreads();
  const u32* W3w = (const u32*)cW3;
  #pragma unroll
  for (int i = 0; i < 32; i++) Wl[t + i * 256] = W3w[t + i * 256];
  __syncthreads();

  { // layer 3 -> in_s
    const float* inb = &h_s[rg * 2 * 132];
    float acc[2][4];
    #pragma unroll
    for (int i = 0; i < 2; i++){ acc[i][0]=0.f; acc[i][1]=0.f; acc[i][2]=0.f; acc[i][3]=0.f; }
    for (int k = 0; k < 128; k++){
      u32 w0 = Wl[k * 64 + jg * 2], w1 = Wl[k * 64 + jg * 2 + 1];
      float f0=bflo(w0), f1=bfhi(w0), f2=bflo(w1), f3=bfhi(w1);
      #pragma unroll
      for (int i = 0; i < 2; i++){
        float v = inb[i * 132 + k];
        acc[i][0] += v*f0; acc[i][1] += v*f1; acc[i][2] += v*f2; acc[i][3] += v*f3;
      }
    }
    float b0 = bf2f(cb3[j0]), b1 = bf2f(cb3[j0+1]), b2 = bf2f(cb3[j0+2]), b3 = bf2f(cb3[j0+3]);
    #pragma unroll
    for (int i = 0; i < 2; i++){
      float* hp = &in_s[(rg * 2 + i) * 132 + j0];
      hp[0] = acc[i][0] + b0; hp[1] = acc[i][1] + b1;
      hp[2] = acc[i][2] + b2; hp[3] = acc[i][3] + b3;
    }
  }
  __syncthreads();

  if (t < 128){ // LN stats: 8 threads per row, 16 rows
    int r = t >> 3, c0 = (t & 7) * 16;
    float s1 = 0.f, s2 = 0.f;
    #pragma unroll
    for (int i = 0; i < 16; i++){
      float v = in_s[r * 132 + c0 + i];
      s1 += v; s2 += v * v;
    }
    for (int o = 4; o > 0; o >>= 1){
      s1 += __shfl_down(s1, o, 8);
      s2 += __shfl_down(s2, o, 8);
    }
    if ((t & 7) == 0){
      float mu = s1 * 0.0078125f;
      float var = s2 * 0.0078125f - mu * mu;
      sh_mu[r] = mu;
      sh_rs[r] = rsqrtf(var + LN_EPS);
    }
  }
  __syncthreads();

  if (IS_DOWN){
    for (int i = t; i < 16 * 64; i += 256){
      int r = i >> 6, q = i & 63;
      int n = row0 + r;
      u32 outw = 0;
      if (kept[n]){
        float mu = sh_mu[r], rs = sh_rs[r];
        float v0 = (in_s[r*132 + 2*q    ] - mu) * rs * bf2f(cg[2*q    ]) + bf2f(cbe[2*q    ]);
        float v1 = (in_s[r*132 + 2*q + 1] - mu) * rs * bf2f(cg[2*q + 1]) + bf2f(cbe[2*q + 1]);
        outw = f2bf(v0) | (f2bf(v1) << 16);
      }
      Rout[(size_t)n * 64 + q] = outw;
    }
  } else {
    int isf = st->is_f32;
    for (int i = t; i < 16 * 64; i += 256){
      int r = i >> 6, q = i & 63;
      int n = row0 + r;
      float mu = sh_mu[r], rs = sh_rs[r];
      float v0 = (in_s[r*132 + 2*q    ] - mu) * rs * bf2f(cg[2*q    ]) + bf2f(cbe[2*q    ]);
      float v1 = (in_s[r*132 + 2*q + 1] - mu) * rs * bf2f(cg[2*q + 1]) + bf2f(cbe[2*q + 1]);
      if (isf){
        float2 v; v.x = v0; v.y = v1;
        *(float2*)((float*)fout + (size_t)n * 128 + 2*q) = v;
      } else {
        ((u32*)fout)[(size_t)n * 64 + q] = f2bf(v0) | (f2bf(v1) << 16);
      }
    }
  }
}

// ---------------- host launch ----------------

extern "C" void kernel_launch(void* const* d_in, const int* in_sizes, int n_in,
                              void* d_out, int out_size, void* d_ws, size_t ws_size,
                              hipStream_t stream)
{
  const void* x     = d_in[0];
  const int* eidx   = (const int*)d_in[1];
  const void* poolp = d_in[2];
  const int* senders = eidx;
  const int* receivers = eidx + N_EDGES;

  char* ws = (char*)d_ws;
  SelState* st = (SelState*)(ws + ST_OFF);
  u16*  canon  = (u16*) (ws + CANON_OFF);
  u64*  keys   = (u64*) (ws + KEYS_OFF);
  float* tval  = (float*)(ws + TVAL_OFF);
  u32*  kept   = (u32*) (ws + KEPT_OFF);
  u32*  A      = (u32*) (ws + A_OFF);    // N x 64 bf16-pair accumulator
  u32*  S      = (u32*) d_out;           // bf16 staging; final output overwrites

  P16 ps;
  for (int i = 0; i < 16; i++) ps.q[i] = d_in[3 + i];

  k_detect<<<1, 256, 0, stream>>>((const u32*)x, st);
  k_init<<<1, 256, 0, stream>>>(st);
  k_canon<<<(C_TOT + 255) / 256, 256, 0, stream>>>(ps, st, canon);
  k_pnorm<<<1, 128, 0, stream>>>(poolp, st);
  k_score<<<N_NODES / 4, 256, 0, stream>>>(x, poolp, st, keys, tval);
  for (int pass = 0; pass < 8; pass++){
    k_radix_pass<<<N_NODES / 256, 256, 0, stream>>>(keys, st, 56 - 8 * pass);
    k_radix_scan<<<1, 1, 0, stream>>>(st);
  }
  k_mark<<<N_NODES / 256, 256, 0, stream>>>(keys, st, kept);
  k_tie<<<1, 256, 0, stream>>>(st, kept);

  // ---- down conv ----
  k_proj_down<<<N_NODES / 64, 256, 0, stream>>>(x, tval, canon + C_DW1, st, S);
  hipMemsetAsync(A, 0, (size_t)N_NODES * 64 * 4, stream);
  k_scatter_down<<<(int)((size_t)N_EDGES * 64 / 256), 256, 0, stream>>>(senders, receivers, kept, S, A);
  k_mlp<1><<<N_NODES / 16, 256, 0, stream>>>(A, canon + C_DB1, canon + C_DW2, canon + C_DB2,
      canon + C_DW3, canon + C_DB3, canon + C_DG, canon + C_DBE, kept, st, S, nullptr);

  // ---- up conv ----
  k_proj_up<<<N_NODES / 64, 256, 0, stream>>>(S, x, canon + C_UW1, st, S);
  hipMemsetAsync(A, 0, (size_t)N_NODES * 64 * 4, stream);
  k_scatter_up<<<(int)((size_t)N_EDGES * 64 / 256), 256, 0, stream>>>(senders, receivers, S, A);
  k_mlp<0><<<N_NODES / 16, 256, 0, stream>>>(A, canon + C_UB1, canon + C_UW2, canon + C_UB2,
      canon + C_UW3, canon + C_UB3, canon + C_UG, canon + C_UBE, kept, st, nullptr, d_out);
}

// Round 4
// 1317.592 us; speedup vs baseline: 1.6271x; 1.6271x over previous
//
#include <hip/hip_runtime.h>

#define N_NODES 131072
#define N_EDGES 524288
#define K_TOP   65536
#define LN_EPS  1e-5f

typedef unsigned int u32;
typedef unsigned short u16;
typedef unsigned long long u64;

// ---- ws layout (35MB total; small/critical at the bottom) ----
#define ST_OFF    0             // SelState (~52KB, reserve 64KB)
#define CANON_OFF (64u<<10)     // 115968 bf16 elems (~232KB) -> [64K, 320K)
#define PART_OFF  (320u<<10)    // 256x256 u32 partial hists = 256KB -> [320K, 576K)
#define KEYS_OFF  (1u<<20)      // N u64 = 1MB
#define TVAL_OFF  (2u<<20)      // N f32 = 512KB
#define KEPT_OFF  ((2u<<20)+(512u<<10)) // N u32 = 512KB
#define A_OFF     (3u<<20)      // N x 64 u32 (bf16-pair accumulator) = 32MB
// d_out serves as S (proj bf16) -> R (recovered bf16) -> S2 -> final output.

// canonical parameter block offsets (bf16 elements)
#define C_DW1 0
#define C_DB1 16384
#define C_DW2 16512
#define C_DB2 32896
#define C_DW3 33024
#define C_DB3 49408
#define C_DG  49536
#define C_DBE 49664
#define C_UW1 49792
#define C_UB1 82560
#define C_UW2 82688
#define C_UB2 99072
#define C_UW3 99200
#define C_UB3 115584
#define C_UG  115712
#define C_UBE 115840
#define C_TOT 115968

__device__ __forceinline__ float bflo(u32 u){ return __uint_as_float(u << 16); }
__device__ __forceinline__ float bfhi(u32 u){ return __uint_as_float(u & 0xFFFF0000u); }
__device__ __forceinline__ float bf2f(u16 v){ return __uint_as_float(((u32)v) << 16); }
__device__ __forceinline__ u32 f2bf(float f){
  u32 u = __float_as_uint(f);
  return (u + 0x7FFFu + ((u >> 16) & 1u)) >> 16;
}
__device__ __forceinline__ float gelu_f(float x){
  return 0.5f * x * (1.0f + erff(x * 0.7071067811865476f));
}

struct SelState {
  u64 prefix;
  u32 krem, eqcnt;
  int is_f32;
  u32 pad;
  double inv_norm;
  u32 eqlist[4096];
  u64 eqkey[4096];
};

struct P16 { const void* q[16]; };

// ---------------- dtype detection ----------------
__global__ void k_detect(const u32* __restrict__ xw, SelState* st){
  int t = threadIdx.x;  // 256
  int cnt = 0;
  for (int i = t; i < 4096; i += 256){
    u32 w = xw[(size_t)i * 2048];
    u32 e = (w >> 23) & 0xFFu;
    if (e >= 97u && e <= 135u) cnt++;
  }
  __shared__ int sh[256];
  sh[t] = cnt; __syncthreads();
  for (int o = 128; o > 0; o >>= 1){ if (t < o) sh[t] += sh[t+o]; __syncthreads(); }
  if (t == 0) st->is_f32 = (sh[0] >= 3072) ? 1 : 0;
}

__global__ void k_init(SelState* st){
  if (threadIdx.x == 0){ st->prefix = 0; st->krem = K_TOP; st->eqcnt = 0; }
}

// convert all 16 parameter arrays to canonical bf16
__global__ void k_canon(P16 ps, const SelState* __restrict__ st, u16* __restrict__ canon){
  const int off[17] = {C_DW1,C_DB1,C_DW2,C_DB2,C_DW3,C_DB3,C_DG,C_DBE,
                       C_UW1,C_UB1,C_UW2,C_UB2,C_UW3,C_UB3,C_UG,C_UBE,C_TOT};
  int i = blockIdx.x * 256 + threadIdx.x;
  if (i >= C_TOT) return;
  int seg = 0;
  #pragma unroll
  for (int s2 = 0; s2 < 16; s2++) if (i >= off[s2+1]) seg = s2 + 1;
  int j = i - off[seg];
  if (st->is_f32) canon[i] = (u16)f2bf(((const float*)ps.q[seg])[j]);
  else            canon[i] = ((const u16*)ps.q[seg])[j];
}

__global__ void k_pnorm(const void* __restrict__ p, SelState* st){
  int t = threadIdx.x;  // 128
  float pv = st->is_f32 ? ((const float*)p)[t] : bf2f(((const u16*)p)[t]);
  __shared__ double sh[128];
  sh[t] = (double)pv * (double)pv;
  __syncthreads();
  for (int o = 64; o > 0; o >>= 1){ if (t < o) sh[t] += sh[t+o]; __syncthreads(); }
  if (t == 0) st->inv_norm = 1.0 / sqrt(sh[0]);
}

// f64 dot on RAW data so the top-k SET matches the f64 np reference exactly
__global__ __launch_bounds__(256) void k_score(const void* __restrict__ xraw, const void* __restrict__ praw,
                        const SelState* __restrict__ st,
                        u64* __restrict__ keys, float* __restrict__ tval){
  int t = threadIdx.x, lane = t & 63, w = t >> 6;
  int n = blockIdx.x * 4 + w;
  double d;
  if (st->is_f32){
    const float* xf = (const float*)xraw + (size_t)n * 128;
    const float* pf = (const float*)praw;
    d = (double)xf[lane] * (double)pf[lane]
      + (double)xf[64 + lane] * (double)pf[64 + lane];
  } else {
    const u32* xw = (const u32*)xraw + (size_t)n * 64;
    const u32* pw = (const u32*)praw;
    u32 xx = xw[lane], pv = pw[lane];
    d = (double)bflo(xx) * (double)bflo(pv) + (double)bfhi(xx) * (double)bfhi(pv);
  }
  for (int o = 32; o > 0; o >>= 1) d += __shfl_down(d, o, 64);
  if (lane == 0){
    double sc = d * st->inv_norm;
    u64 u = (u64)__double_as_longlong(sc);
    u64 key = (u & 0x8000000000000000ULL) ? ~u : (u | 0x8000000000000000ULL);
    keys[n] = key;
    tval[n] = tanhf((float)sc);
  }
}

// ---------------- contention-free 4-pass radix select (top 32 bits) ----------------
// 256 blocks build per-block LDS histograms -> disjoint partial writes (no global atomics)
__global__ __launch_bounds__(256) void k_histp(const u64* __restrict__ keys,
                                               const SelState* __restrict__ st,
                                               u32* __restrict__ partial, int pass){
  __shared__ u32 h[256];
  int t = threadIdx.x;
  h[t] = 0;
  __syncthreads();
  u64 pref = st->prefix;
  int sh_d = 56 - 8 * pass;
  for (int n = blockIdx.x * 256 + t; n < N_NODES; n += 256 * 256){
    u64 k = keys[n];
    bool m = (pass == 0) ? true : ((k >> (sh_d + 8)) == pref);
    if (m) atomicAdd(&h[(u32)((k >> sh_d) & 255)], 1u);
  }
  __syncthreads();
  partial[blockIdx.x * 256 + t] = h[t];
}

__global__ void k_scanp(const u32* __restrict__ partial, SelState* st){
  __shared__ u32 tot[256];
  int t = threadIdx.x;
  u32 s = 0;
  for (int b = 0; b < 256; b++) s += partial[b * 256 + t];  // coalesced across threads
  tot[t] = s;
  __syncthreads();
  if (t == 0){
    u32 target = st->krem;
    u32 cum = 0; int chosen = 255;
    for (int b = 255; b >= 0; b--){
      if (cum + tot[b] >= target){ chosen = b; break; }
      cum += tot[b];
    }
    st->prefix = (st->prefix << 8) | (u64)(u32)chosen;
    st->krem = target - cum;
  }
}

__global__ void k_mark(const u64* __restrict__ keys, SelState* st, u32* __restrict__ kept){
  int n = blockIdx.x * blockDim.x + threadIdx.x;
  u64 k = keys[n];
  u32 t32 = (u32)(k >> 32);
  u32 T = (u32)st->prefix;   // after 4 passes prefix = top-32 bits
  kept[n] = (t32 > T) ? 1u : 0u;
  if (t32 == T){
    u32 i = atomicAdd(&st->eqcnt, 1u);
    if (i < 4096){ st->eqlist[i] = (u32)n; st->eqkey[i] = k; }
  }
}

// exact rank among boundary-bucket keys: key desc, index asc (== lax.top_k tie-break)
__global__ void k_tie(SelState* st, u32* __restrict__ kept){
  u32 m = st->eqcnt; if (m > 4096) m = 4096;
  u32 r = st->krem;
  for (u32 i = threadIdx.x; i < m; i += blockDim.x){
    u64 ki = st->eqkey[i]; u32 ii = st->eqlist[i];
    u32 rank = 0;
    for (u32 j = 0; j < m; j++){
      u64 kj = st->eqkey[j];
      rank += (kj > ki || (kj == ki && st->eqlist[j] < ii)) ? 1u : 0u;
    }
    if (rank < r) kept[ii] = 1u;
  }
}

// ---------------- projection GEMMs (bf16-packed LDS, fp32 acc) ----------------
// S[n] = bf16(x[n]*tval[n] @ dW1)
__global__ __launch_bounds__(256) void k_proj_down(
    const void* __restrict__ xraw, const float* __restrict__ tval,
    const u16* __restrict__ Wc, const SelState* __restrict__ st,
    u32* __restrict__ S)
{
  __shared__ u32 in_s[64 * 66];
  __shared__ u32 Wl[128 * 64];
  int t = threadIdx.x;
  int row0 = blockIdx.x * 64;
  const u32* W32 = (const u32*)Wc;
  #pragma unroll
  for (int i = 0; i < 32; i++) Wl[t + i * 256] = W32[t + i * 256];

  if (st->is_f32){
    const float* xf = (const float*)xraw + (size_t)row0 * 128;
    for (int i = t; i < 64 * 64; i += 256){
      int r = i >> 6, cp = i & 63;
      float tv = tval[row0 + r];
      float2 v = *(const float2*)(xf + (size_t)r * 128 + 2 * cp);
      in_s[r * 66 + cp] = f2bf(v.x * tv) | (f2bf(v.y * tv) << 16);
    }
  } else {
    const u32* xw = (const u32*)xraw + (size_t)row0 * 64;
    for (int i = t; i < 64 * 64; i += 256){
      int r = i >> 6, cp = i & 63;
      u32 u = xw[(size_t)r * 64 + cp];
      float tv = tval[row0 + r];
      in_s[r * 66 + cp] = f2bf(bflo(u) * tv) | (f2bf(bfhi(u) * tv) << 16);
    }
  }
  __syncthreads();

  int jg = t & 31, rg = t >> 5;
  const u32* inb = &in_s[rg * 8 * 66];
  float acc[8][4];
  #pragma unroll
  for (int i = 0; i < 8; i++){ acc[i][0]=0.f; acc[i][1]=0.f; acc[i][2]=0.f; acc[i][3]=0.f; }

  for (int k2 = 0; k2 < 64; k2++){
    u32 wa = Wl[(2*k2)*64 + jg*2],   wb = Wl[(2*k2)*64 + jg*2 + 1];
    u32 wc = Wl[(2*k2+1)*64 + jg*2], wd = Wl[(2*k2+1)*64 + jg*2 + 1];
    float a0=bflo(wa), a1=bfhi(wa), a2=bflo(wb), a3=bfhi(wb);
    float c0=bflo(wc), c1=bfhi(wc), c2=bflo(wd), c3=bfhi(wd);
    #pragma unroll
    for (int i = 0; i < 8; i++){
      u32 vw = inb[i*66 + k2];
      float v0 = bflo(vw), v1 = bfhi(vw);
      acc[i][0] += v0*a0 + v1*c0;
      acc[i][1] += v0*a1 + v1*c1;
      acc[i][2] += v0*a2 + v1*c2;
      acc[i][3] += v0*a3 + v1*c3;
    }
  }
  #pragma unroll
  for (int i = 0; i < 8; i++){
    size_t r = row0 + rg * 8 + i;
    S[r * 64 + jg * 2    ] = f2bf(acc[i][0]) | (f2bf(acc[i][1]) << 16);
    S[r * 64 + jg * 2 + 1] = f2bf(acc[i][2]) | (f2bf(acc[i][3]) << 16);
  }
}

// S2[n] = bf16(R[n] @ uW1[0:128,:] + x[n] @ uW1[128:256,:]); in-place on d_out (per-block rows)
__global__ __launch_bounds__(256) void k_proj_up(
    const u32* __restrict__ R, const void* __restrict__ xraw,
    const u16* __restrict__ Wc, const SelState* __restrict__ st,
    u32* __restrict__ S2)
{
  __shared__ u32 in_s[64 * 66];
  __shared__ u32 Wl[128 * 64];
  int t = threadIdx.x;
  int row0 = blockIdx.x * 64;
  int jg = t & 31, rg = t >> 5;

  float acc[8][4];
  #pragma unroll
  for (int i = 0; i < 8; i++){ acc[i][0]=0.f; acc[i][1]=0.f; acc[i][2]=0.f; acc[i][3]=0.f; }

  for (int ph = 0; ph < 2; ph++){
    const u32* W32 = (const u32*)Wc + (size_t)ph * 8192;
    #pragma unroll
    for (int i = 0; i < 32; i++) Wl[t + i * 256] = W32[t + i * 256];
    if (ph == 0){
      for (int i = t; i < 64 * 64; i += 256){
        int r = i >> 6, cp = i & 63;
        in_s[r * 66 + cp] = R[(size_t)(row0 + r) * 64 + cp];
      }
    } else if (st->is_f32){
      const float* xf = (const float*)xraw + (size_t)row0 * 128;
      for (int i = t; i < 64 * 64; i += 256){
        int r = i >> 6, cp = i & 63;
        float2 v = *(const float2*)(xf + (size_t)r * 128 + 2 * cp);
        in_s[r * 66 + cp] = f2bf(v.x) | (f2bf(v.y) << 16);
      }
    } else {
      const u32* xw = (const u32*)xraw + (size_t)row0 * 64;
      for (int i = t; i < 64 * 64; i += 256){
        int r = i >> 6, cp = i & 63;
        in_s[r * 66 + cp] = xw[(size_t)r * 64 + cp];
      }
    }
    __syncthreads();
    const u32* inb = &in_s[rg * 8 * 66];
    for (int k2 = 0; k2 < 64; k2++){
      u32 wa = Wl[(2*k2)*64 + jg*2],   wb = Wl[(2*k2)*64 + jg*2 + 1];
      u32 wc = Wl[(2*k2+1)*64 + jg*2], wd = Wl[(2*k2+1)*64 + jg*2 + 1];
      float a0=bflo(wa), a1=bfhi(wa), a2=bflo(wb), a3=bfhi(wb);
      float c0=bflo(wc), c1=bfhi(wc), c2=bflo(wd), c3=bfhi(wd);
      #pragma unroll
      for (int i = 0; i < 8; i++){
        u32 vw = inb[i*66 + k2];
        float v0 = bflo(vw), v1 = bfhi(vw);
        acc[i][0] += v0*a0 + v1*c0;
        acc[i][1] += v0*a1 + v1*c1;
        acc[i][2] += v0*a2 + v1*c2;
        acc[i][3] += v0*a3 + v1*c3;
      }
    }
    __syncthreads();
  }
  #pragma unroll
  for (int i = 0; i < 8; i++){
    size_t r = row0 + rg * 8 + i;
    S2[r * 64 + jg * 2    ] = f2bf(acc[i][0]) | (f2bf(acc[i][1]) << 16);
    S2[r * 64 + jg * 2 + 1] = f2bf(acc[i][2]) | (f2bf(acc[i][3]) << 16);
  }
}

// ---------------- scatter via bf16-pair CAS (32MB accumulator) ----------------
__device__ __forceinline__ void cas_add2(u32* addr, float m0, float m1){
  u32 old = *addr, assumed;
  do {
    assumed = old;
    u32 nv = f2bf(bflo(assumed) + m0) | (f2bf(bfhi(assumed) + m1) << 16);
    if (nv == assumed) break;
    old = atomicCAS(addr, assumed, nv);
  } while (old != assumed);
}

__global__ __launch_bounds__(256) void k_scatter_down(
    const int* __restrict__ se, const int* __restrict__ re,
    const u32* __restrict__ kept,
    const u32* __restrict__ S, u32* __restrict__ A)
{
  long long id = (long long)blockIdx.x * 256 + threadIdx.x;
  int e = (int)(id >> 6), q = (int)(id & 63);
  int s = se[e], r = re[e];
  if (kept[s] & kept[r]){
    u32 ms = S[(size_t)s * 64 + q];
    u32 mr = S[(size_t)r * 64 + q];
    cas_add2(&A[(size_t)r * 64 + q], bflo(ms), bfhi(ms));
    cas_add2(&A[(size_t)s * 64 + q], bflo(mr), bfhi(mr));
  }
}

__global__ __launch_bounds__(256) void k_scatter_up(
    const int* __restrict__ se, const int* __restrict__ re,
    const u32* __restrict__ S, u32* __restrict__ A)
{
  long long id = (long long)blockIdx.x * 256 + threadIdx.x;
  int e = (int)(id >> 6), q = (int)(id & 63);
  int s = se[e], r = re[e];
  u32 ms = S[(size_t)s * 64 + q];
  u32 mr = S[(size_t)r * 64 + q];
  cas_add2(&A[(size_t)r * 64 + q], bflo(ms), bfhi(ms));
  cas_add2(&A[(size_t)s * 64 + q], bflo(mr), bfhi(mr));
}

// ---------------- fused MLP tail: gelu(agg+b1) -> @W2 gelu -> @W3 -> LN ----------------
template<int IS_DOWN>
__global__ __launch_bounds__(256) void k_mlp(
    const u32* __restrict__ A,
    const u16* __restrict__ cb1, const u16* __restrict__ cW2, const u16* __restrict__ cb2,
    const u16* __restrict__ cW3, const u16* __restrict__ cb3,
    const u16* __restrict__ cg, const u16* __restrict__ cbe,
    const u32* __restrict__ kept, const SelState* __restrict__ st,
    u32* __restrict__ Rout, void* __restrict__ fout)
{
  __shared__ float in_s[16 * 132];
  __shared__ float h_s[16 * 132];
  __shared__ u32 Wl[128 * 64];
  __shared__ float sh_mu[16], sh_rs[16];
  int t = threadIdx.x;
  int row0 = blockIdx.x * 16;

  for (int i = t; i < 16 * 64; i += 256){
    int r = i >> 6, q = i & 63;
    u32 w = A[(size_t)(row0 + r) * 64 + q];
    in_s[r * 132 + 2*q    ] = gelu_f(bflo(w) + bf2f(cb1[2*q    ]));
    in_s[r * 132 + 2*q + 1] = gelu_f(bfhi(w) + bf2f(cb1[2*q + 1]));
  }
  const u32* W2w = (const u32*)cW2;
  #pragma unroll
  for (int i = 0; i < 32; i++) Wl[t + i * 256] = W2w[t + i * 256];
  __syncthreads();

  int jg = t & 31, rg = t >> 5, j0 = jg * 4;

  { // layer 2
    const float* inb = &in_s[rg * 2 * 132];
    float acc[2][4];
    #pragma unroll
    for (int i = 0; i < 2; i++){ acc[i][0]=0.f; acc[i][1]=0.f; acc[i][2]=0.f; acc[i][3]=0.f; }
    for (int k = 0; k < 128; k++){
      u32 w0 = Wl[k * 64 + jg * 2], w1 = Wl[k * 64 + jg * 2 + 1];
      float f0=bflo(w0), f1=bfhi(w0), f2=bflo(w1), f3=bfhi(w1);
      #pragma unroll
      for (int i = 0; i < 2; i++){
        float v = inb[i * 132 + k];
        acc[i][0] += v*f0; acc[i][1] += v*f1; acc[i][2] += v*f2; acc[i][3] += v*f3;
      }
    }
    float b0 = bf2f(cb2[j0]), b1 = bf2f(cb2[j0+1]), b2 = bf2f(cb2[j0+2]), b3 = bf2f(cb2[j0+3]);
    #pragma unroll
    for (int i = 0; i < 2; i++){
      float* hp = &h_s[(rg * 2 + i) * 132 + j0];
      hp[0] = gelu_f(acc[i][0] + b0); hp[1] = gelu_f(acc[i][1] + b1);
      hp[2] = gelu_f(acc[i][2] + b2); hp[3] = gelu_f(acc[i][3] + b3);
    }
  }
  __syncthreads();
  const u32* W3w = (const u32*)cW3;
  #pragma unroll
  for (int i = 0; i < 32; i++) Wl[t + i * 256] = W3w[t + i * 256];
  __syncthreads();

  { // layer 3 -> in_s
    const float* inb = &h_s[rg * 2 * 132];
    float acc[2][4];
    #pragma unroll
    for (int i = 0; i < 2; i++){ acc[i][0]=0.f; acc[i][1]=0.f; acc[i][2]=0.f; acc[i][3]=0.f; }
    for (int k = 0; k < 128; k++){
      u32 w0 = Wl[k * 64 + jg * 2], w1 = Wl[k * 64 + jg * 2 + 1];
      float f0=bflo(w0), f1=bfhi(w0), f2=bflo(w1), f3=bfhi(w1);
      #pragma unroll
      for (int i = 0; i < 2; i++){
        float v = inb[i * 132 + k];
        acc[i][0] += v*f0; acc[i][1] += v*f1; acc[i][2] += v*f2; acc[i][3] += v*f3;
      }
    }
    float b0 = bf2f(cb3[j0]), b1 = bf2f(cb3[j0+1]), b2 = bf2f(cb3[j0+2]), b3 = bf2f(cb3[j0+3]);
    #pragma unroll
    for (int i = 0; i < 2; i++){
      float* hp = &in_s[(rg * 2 + i) * 132 + j0];
      hp[0] = acc[i][0] + b0; hp[1] = acc[i][1] + b1;
      hp[2] = acc[i][2] + b2; hp[3] = acc[i][3] + b3;
    }
  }
  __syncthreads();

  if (t < 128){ // LN stats: 8 threads per row, 16 rows
    int r = t >> 3, c0 = (t & 7) * 16;
    float s1 = 0.f, s2 = 0.f;
    #pragma unroll
    for (int i = 0; i < 16; i++){
      float v = in_s[r * 132 + c0 + i];
      s1 += v; s2 += v * v;
    }
    for (int o = 4; o > 0; o >>= 1){
      s1 += __shfl_down(s1, o, 8);
      s2 += __shfl_down(s2, o, 8);
    }
    if ((t & 7) == 0){
      float mu = s1 * 0.0078125f;
      float var = s2 * 0.0078125f - mu * mu;
      sh_mu[r] = mu;
      sh_rs[r] = rsqrtf(var + LN_EPS);
    }
  }
  __syncthreads();

  if (IS_DOWN){
    for (int i = t; i < 16 * 64; i += 256){
      int r = i >> 6, q = i & 63;
      int n = row0 + r;
      u32 outw = 0;
      if (kept[n]){
        float mu = sh_mu[r], rs = sh_rs[r];
        float v0 = (in_s[r*132 + 2*q    ] - mu) * rs * bf2f(cg[2*q    ]) + bf2f(cbe[2*q    ]);
        float v1 = (in_s[r*132 + 2*q + 1] - mu) * rs * bf2f(cg[2*q + 1]) + bf2f(cbe[2*q + 1]);
        outw = f2bf(v0) | (f2bf(v1) << 16);
      }
      Rout[(size_t)n * 64 + q] = outw;
    }
  } else {
    int isf = st->is_f32;
    for (int i = t; i < 16 * 64; i += 256){
      int r = i >> 6, q = i & 63;
      int n = row0 + r;
      float mu = sh_mu[r], rs = sh_rs[r];
      float v0 = (in_s[r*132 + 2*q    ] - mu) * rs * bf2f(cg[2*q    ]) + bf2f(cbe[2*q    ]);
      float v1 = (in_s[r*132 + 2*q + 1] - mu) * rs * bf2f(cg[2*q + 1]) + bf2f(cbe[2*q + 1]);
      if (isf){
        float2 v; v.x = v0; v.y = v1;
        *(float2*)((float*)fout + (size_t)n * 128 + 2*q) = v;
      } else {
        ((u32*)fout)[(size_t)n * 64 + q] = f2bf(v0) | (f2bf(v1) << 16);
      }
    }
  }
}

// ---------------- host launch ----------------

extern "C" void kernel_launch(void* const* d_in, const int* in_sizes, int n_in,
                              void* d_out, int out_size, void* d_ws, size_t ws_size,
                              hipStream_t stream)
{
  const void* x     = d_in[0];
  const int* eidx   = (const int*)d_in[1];
  const void* poolp = d_in[2];
  const int* senders = eidx;
  const int* receivers = eidx + N_EDGES;

  char* ws = (char*)d_ws;
  SelState* st = (SelState*)(ws + ST_OFF);
  u16*  canon  = (u16*) (ws + CANON_OFF);
  u32*  partial= (u32*) (ws + PART_OFF);
  u64*  keys   = (u64*) (ws + KEYS_OFF);
  float* tval  = (float*)(ws + TVAL_OFF);
  u32*  kept   = (u32*) (ws + KEPT_OFF);
  u32*  A      = (u32*) (ws + A_OFF);    // N x 64 bf16-pair accumulator
  u32*  S      = (u32*) d_out;           // bf16 staging; final output overwrites

  P16 ps;
  for (int i = 0; i < 16; i++) ps.q[i] = d_in[3 + i];

  k_detect<<<1, 256, 0, stream>>>((const u32*)x, st);
  k_init<<<1, 64, 0, stream>>>(st);
  k_canon<<<(C_TOT + 255) / 256, 256, 0, stream>>>(ps, st, canon);
  k_pnorm<<<1, 128, 0, stream>>>(poolp, st);
  k_score<<<N_NODES / 4, 256, 0, stream>>>(x, poolp, st, keys, tval);
  for (int pass = 0; pass < 4; pass++){
    k_histp<<<256, 256, 0, stream>>>(keys, st, partial, pass);
    k_scanp<<<1, 256, 0, stream>>>(partial, st);
  }
  k_mark<<<N_NODES / 256, 256, 0, stream>>>(keys, st, kept);
  k_tie<<<1, 256, 0, stream>>>(st, kept);

  // ---- down conv ----
  k_proj_down<<<N_NODES / 64, 256, 0, stream>>>(x, tval, canon + C_DW1, st, S);
  hipMemsetAsync(A, 0, (size_t)N_NODES * 64 * 4, stream);
  k_scatter_down<<<(int)((size_t)N_EDGES * 64 / 256), 256, 0, stream>>>(senders, receivers, kept, S, A);
  k_mlp<1><<<N_NODES / 16, 256, 0, stream>>>(A, canon + C_DB1, canon + C_DW2, canon + C_DB2,
      canon + C_DW3, canon + C_DB3, canon + C_DG, canon + C_DBE, kept, st, S, nullptr);

  // ---- up conv ----
  k_proj_up<<<N_NODES / 64, 256, 0, stream>>>(S, x, canon + C_UW1, st, S);
  hipMemsetAsync(A, 0, (size_t)N_NODES * 64 * 4, stream);
  k_scatter_up<<<(int)((size_t)N_EDGES * 64 / 256), 256, 0, stream>>>(senders, receivers, S, A);
  k_mlp<0><<<N_NODES / 16, 256, 0, stream>>>(A, canon + C_UB1, canon + C_UW2, canon + C_UB2,
      canon + C_UW3, canon + C_UB3, canon + C_UG, canon + C_UBE, kept, st, nullptr, d_out);
}

// Round 5
// 1147.963 us; speedup vs baseline: 1.8675x; 1.1478x over previous
//
#include <hip/hip_runtime.h>

#define N_NODES 131072
#define N_EDGES 524288
#define K_TOP   65536
#define LN_EPS  1e-5f

typedef unsigned int u32;
typedef unsigned short u16;
typedef unsigned long long u64;

// ---- ws layout (35MB total; small/critical at the bottom) ----
#define ST_OFF    0             // SelState (~52KB, reserve 64KB)
#define CANON_OFF (64u<<10)     // 115968 bf16 elems (~232KB) -> [64K, 320K)
#define PART_OFF  (320u<<10)    // 256x256 u32 partial hists = 256KB -> [320K, 576K)
#define KEYS_OFF  (1u<<20)      // N u64 = 1MB
#define TVAL_OFF  (2u<<20)      // N f32 = 512KB
#define KEPT_OFF  ((2u<<20)+(512u<<10)) // N u32 = 512KB
#define A_OFF     (3u<<20)      // N x 64 u32 (bf16-pair accumulator) = 32MB
// d_out serves as S (proj bf16) -> R (recovered bf16) -> S2 -> final output.

// canonical parameter block offsets (bf16 elements)
#define C_DW1 0
#define C_DB1 16384
#define C_DW2 16512
#define C_DB2 32896
#define C_DW3 33024
#define C_DB3 49408
#define C_DG  49536
#define C_DBE 49664
#define C_UW1 49792
#define C_UB1 82560
#define C_UW2 82688
#define C_UB2 99072
#define C_UW3 99200
#define C_UB3 115584
#define C_UG  115712
#define C_UBE 115840
#define C_TOT 115968

__device__ __forceinline__ float bflo(u32 u){ return __uint_as_float(u << 16); }
__device__ __forceinline__ float bfhi(u32 u){ return __uint_as_float(u & 0xFFFF0000u); }
__device__ __forceinline__ float bf2f(u16 v){ return __uint_as_float(((u32)v) << 16); }
__device__ __forceinline__ u32 f2bf(float f){
  u32 u = __float_as_uint(f);
  return (u + 0x7FFFu + ((u >> 16) & 1u)) >> 16;
}
__device__ __forceinline__ float gelu_f(float x){
  return 0.5f * x * (1.0f + erff(x * 0.7071067811865476f));
}

// native packed-bf16 atomic add (gfx942+/gfx950): fire-and-forget, no CAS loop.
// ISA operand order: vaddr pair first, vdata second ("mem += v0, addr first").
__device__ __forceinline__ void pk_add_bf16(u32* addr, u32 val){
  asm volatile("global_atomic_pk_add_bf16 %0, %1, off"
               :: "v"(addr), "v"(val) : "memory");
}

struct SelState {
  u64 prefix;
  u32 krem, eqcnt;
  int is_f32;
  u32 pad;
  double inv_norm;
  u32 eqlist[4096];
  u64 eqkey[4096];
};

struct P16 { const void* q[16]; };

// ---------------- dtype detection ----------------
__global__ void k_detect(const u32* __restrict__ xw, SelState* st){
  int t = threadIdx.x;  // 256
  int cnt = 0;
  for (int i = t; i < 4096; i += 256){
    u32 w = xw[(size_t)i * 2048];
    u32 e = (w >> 23) & 0xFFu;
    if (e >= 97u && e <= 135u) cnt++;
  }
  __shared__ int sh[256];
  sh[t] = cnt; __syncthreads();
  for (int o = 128; o > 0; o >>= 1){ if (t < o) sh[t] += sh[t+o]; __syncthreads(); }
  if (t == 0) st->is_f32 = (sh[0] >= 3072) ? 1 : 0;
}

__global__ void k_init(SelState* st){
  if (threadIdx.x == 0){ st->prefix = 0; st->krem = K_TOP; st->eqcnt = 0; }
}

// convert all 16 parameter arrays to canonical bf16
__global__ void k_canon(P16 ps, const SelState* __restrict__ st, u16* __restrict__ canon){
  const int off[17] = {C_DW1,C_DB1,C_DW2,C_DB2,C_DW3,C_DB3,C_DG,C_DBE,
                       C_UW1,C_UB1,C_UW2,C_UB2,C_UW3,C_UB3,C_UG,C_UBE,C_TOT};
  int i = blockIdx.x * 256 + threadIdx.x;
  if (i >= C_TOT) return;
  int seg = 0;
  #pragma unroll
  for (int s2 = 0; s2 < 16; s2++) if (i >= off[s2+1]) seg = s2 + 1;
  int j = i - off[seg];
  if (st->is_f32) canon[i] = (u16)f2bf(((const float*)ps.q[seg])[j]);
  else            canon[i] = ((const u16*)ps.q[seg])[j];
}

__global__ void k_pnorm(const void* __restrict__ p, SelState* st){
  int t = threadIdx.x;  // 128
  float pv = st->is_f32 ? ((const float*)p)[t] : bf2f(((const u16*)p)[t]);
  __shared__ double sh[128];
  sh[t] = (double)pv * (double)pv;
  __syncthreads();
  for (int o = 64; o > 0; o >>= 1){ if (t < o) sh[t] += sh[t+o]; __syncthreads(); }
  if (t == 0) st->inv_norm = 1.0 / sqrt(sh[0]);
}

// f64 dot on RAW data so the top-k SET matches the f64 np reference exactly
__global__ __launch_bounds__(256) void k_score(const void* __restrict__ xraw, const void* __restrict__ praw,
                        const SelState* __restrict__ st,
                        u64* __restrict__ keys, float* __restrict__ tval){
  int t = threadIdx.x, lane = t & 63, w = t >> 6;
  int n = blockIdx.x * 4 + w;
  double d;
  if (st->is_f32){
    const float* xf = (const float*)xraw + (size_t)n * 128;
    const float* pf = (const float*)praw;
    d = (double)xf[lane] * (double)pf[lane]
      + (double)xf[64 + lane] * (double)pf[64 + lane];
  } else {
    const u32* xw = (const u32*)xraw + (size_t)n * 64;
    const u32* pw = (const u32*)praw;
    u32 xx = xw[lane], pv = pw[lane];
    d = (double)bflo(xx) * (double)bflo(pv) + (double)bfhi(xx) * (double)bfhi(pv);
  }
  for (int o = 32; o > 0; o >>= 1) d += __shfl_down(d, o, 64);
  if (lane == 0){
    double sc = d * st->inv_norm;
    u64 u = (u64)__double_as_longlong(sc);
    u64 key = (u & 0x8000000000000000ULL) ? ~u : (u | 0x8000000000000000ULL);
    keys[n] = key;
    tval[n] = tanhf((float)sc);
  }
}

// ---------------- contention-free 4-pass radix select (top 32 bits) ----------------
__global__ __launch_bounds__(256) void k_histp(const u64* __restrict__ keys,
                                               const SelState* __restrict__ st,
                                               u32* __restrict__ partial, int pass){
  __shared__ u32 h[256];
  int t = threadIdx.x;
  h[t] = 0;
  __syncthreads();
  u64 pref = st->prefix;
  int sh_d = 56 - 8 * pass;
  for (int n = blockIdx.x * 256 + t; n < N_NODES; n += 256 * 256){
    u64 k = keys[n];
    bool m = (pass == 0) ? true : ((k >> (sh_d + 8)) == pref);
    if (m) atomicAdd(&h[(u32)((k >> sh_d) & 255)], 1u);
  }
  __syncthreads();
  partial[blockIdx.x * 256 + t] = h[t];
}

__global__ void k_scanp(const u32* __restrict__ partial, SelState* st){
  __shared__ u32 tot[256];
  int t = threadIdx.x;
  u32 s = 0;
  for (int b = 0; b < 256; b++) s += partial[b * 256 + t];  // coalesced across threads
  tot[t] = s;
  __syncthreads();
  if (t == 0){
    u32 target = st->krem;
    u32 cum = 0; int chosen = 255;
    for (int b = 255; b >= 0; b--){
      if (cum + tot[b] >= target){ chosen = b; break; }
      cum += tot[b];
    }
    st->prefix = (st->prefix << 8) | (u64)(u32)chosen;
    st->krem = target - cum;
  }
}

__global__ void k_mark(const u64* __restrict__ keys, SelState* st, u32* __restrict__ kept){
  int n = blockIdx.x * blockDim.x + threadIdx.x;
  u64 k = keys[n];
  u32 t32 = (u32)(k >> 32);
  u32 T = (u32)st->prefix;   // after 4 passes prefix = top-32 bits
  kept[n] = (t32 > T) ? 1u : 0u;
  if (t32 == T){
    u32 i = atomicAdd(&st->eqcnt, 1u);
    if (i < 4096){ st->eqlist[i] = (u32)n; st->eqkey[i] = k; }
  }
}

// exact rank among boundary-bucket keys: key desc, index asc (== lax.top_k tie-break)
__global__ void k_tie(SelState* st, u32* __restrict__ kept){
  u32 m = st->eqcnt; if (m > 4096) m = 4096;
  u32 r = st->krem;
  for (u32 i = threadIdx.x; i < m; i += blockDim.x){
    u64 ki = st->eqkey[i]; u32 ii = st->eqlist[i];
    u32 rank = 0;
    for (u32 j = 0; j < m; j++){
      u64 kj = st->eqkey[j];
      rank += (kj > ki || (kj == ki && st->eqlist[j] < ii)) ? 1u : 0u;
    }
    if (rank < r) kept[ii] = 1u;
  }
}

// ---------------- projection GEMMs (bf16-packed LDS, fp32 acc) ----------------
// S[n] = bf16(x[n]*tval[n] @ dW1)
__global__ __launch_bounds__(256) void k_proj_down(
    const void* __restrict__ xraw, const float* __restrict__ tval,
    const u16* __restrict__ Wc, const SelState* __restrict__ st,
    u32* __restrict__ S)
{
  __shared__ u32 in_s[64 * 66];
  __shared__ u32 Wl[128 * 64];
  int t = threadIdx.x;
  int row0 = blockIdx.x * 64;
  const u32* W32 = (const u32*)Wc;
  #pragma unroll
  for (int i = 0; i < 32; i++) Wl[t + i * 256] = W32[t + i * 256];

  if (st->is_f32){
    const float* xf = (const float*)xraw + (size_t)row0 * 128;
    for (int i = t; i < 64 * 64; i += 256){
      int r = i >> 6, cp = i & 63;
      float tv = tval[row0 + r];
      float2 v = *(const float2*)(xf + (size_t)r * 128 + 2 * cp);
      in_s[r * 66 + cp] = f2bf(v.x * tv) | (f2bf(v.y * tv) << 16);
    }
  } else {
    const u32* xw = (const u32*)xraw + (size_t)row0 * 64;
    for (int i = t; i < 64 * 64; i += 256){
      int r = i >> 6, cp = i & 63;
      u32 u = xw[(size_t)r * 64 + cp];
      float tv = tval[row0 + r];
      in_s[r * 66 + cp] = f2bf(bflo(u) * tv) | (f2bf(bfhi(u) * tv) << 16);
    }
  }
  __syncthreads();

  int jg = t & 31, rg = t >> 5;
  const u32* inb = &in_s[rg * 8 * 66];
  float acc[8][4];
  #pragma unroll
  for (int i = 0; i < 8; i++){ acc[i][0]=0.f; acc[i][1]=0.f; acc[i][2]=0.f; acc[i][3]=0.f; }

  for (int k2 = 0; k2 < 64; k2++){
    u32 wa = Wl[(2*k2)*64 + jg*2],   wb = Wl[(2*k2)*64 + jg*2 + 1];
    u32 wc = Wl[(2*k2+1)*64 + jg*2], wd = Wl[(2*k2+1)*64 + jg*2 + 1];
    float a0=bflo(wa), a1=bfhi(wa), a2=bflo(wb), a3=bfhi(wb);
    float c0=bflo(wc), c1=bfhi(wc), c2=bflo(wd), c3=bfhi(wd);
    #pragma unroll
    for (int i = 0; i < 8; i++){
      u32 vw = inb[i*66 + k2];
      float v0 = bflo(vw), v1 = bfhi(vw);
      acc[i][0] += v0*a0 + v1*c0;
      acc[i][1] += v0*a1 + v1*c1;
      acc[i][2] += v0*a2 + v1*c2;
      acc[i][3] += v0*a3 + v1*c3;
    }
  }
  #pragma unroll
  for (int i = 0; i < 8; i++){
    size_t r = row0 + rg * 8 + i;
    S[r * 64 + jg * 2    ] = f2bf(acc[i][0]) | (f2bf(acc[i][1]) << 16);
    S[r * 64 + jg * 2 + 1] = f2bf(acc[i][2]) | (f2bf(acc[i][3]) << 16);
  }
}

// S2[n] = bf16(R[n] @ uW1[0:128,:] + x[n] @ uW1[128:256,:]); in-place on d_out (per-block rows)
__global__ __launch_bounds__(256) void k_proj_up(
    const u32* __restrict__ R, const void* __restrict__ xraw,
    const u16* __restrict__ Wc, const SelState* __restrict__ st,
    u32* __restrict__ S2)
{
  __shared__ u32 in_s[64 * 66];
  __shared__ u32 Wl[128 * 64];
  int t = threadIdx.x;
  int row0 = blockIdx.x * 64;
  int jg = t & 31, rg = t >> 5;

  float acc[8][4];
  #pragma unroll
  for (int i = 0; i < 8; i++){ acc[i][0]=0.f; acc[i][1]=0.f; acc[i][2]=0.f; acc[i][3]=0.f; }

  for (int ph = 0; ph < 2; ph++){
    const u32* W32 = (const u32*)Wc + (size_t)ph * 8192;
    #pragma unroll
    for (int i = 0; i < 32; i++) Wl[t + i * 256] = W32[t + i * 256];
    if (ph == 0){
      for (int i = t; i < 64 * 64; i += 256){
        int r = i >> 6, cp = i & 63;
        in_s[r * 66 + cp] = R[(size_t)(row0 + r) * 64 + cp];
      }
    } else if (st->is_f32){
      const float* xf = (const float*)xraw + (size_t)row0 * 128;
      for (int i = t; i < 64 * 64; i += 256){
        int r = i >> 6, cp = i & 63;
        float2 v = *(const float2*)(xf + (size_t)r * 128 + 2 * cp);
        in_s[r * 66 + cp] = f2bf(v.x) | (f2bf(v.y) << 16);
      }
    } else {
      const u32* xw = (const u32*)xraw + (size_t)row0 * 64;
      for (int i = t; i < 64 * 64; i += 256){
        int r = i >> 6, cp = i & 63;
        in_s[r * 66 + cp] = xw[(size_t)r * 64 + cp];
      }
    }
    __syncthreads();
    const u32* inb = &in_s[rg * 8 * 66];
    for (int k2 = 0; k2 < 64; k2++){
      u32 wa = Wl[(2*k2)*64 + jg*2],   wb = Wl[(2*k2)*64 + jg*2 + 1];
      u32 wc = Wl[(2*k2+1)*64 + jg*2], wd = Wl[(2*k2+1)*64 + jg*2 + 1];
      float a0=bflo(wa), a1=bfhi(wa), a2=bflo(wb), a3=bfhi(wb);
      float c0=bflo(wc), c1=bfhi(wc), c2=bflo(wd), c3=bfhi(wd);
      #pragma unroll
      for (int i = 0; i < 8; i++){
        u32 vw = inb[i*66 + k2];
        float v0 = bflo(vw), v1 = bfhi(vw);
        acc[i][0] += v0*a0 + v1*c0;
        acc[i][1] += v0*a1 + v1*c1;
        acc[i][2] += v0*a2 + v1*c2;
        acc[i][3] += v0*a3 + v1*c3;
      }
    }
    __syncthreads();
  }
  #pragma unroll
  for (int i = 0; i < 8; i++){
    size_t r = row0 + rg * 8 + i;
    S2[r * 64 + jg * 2    ] = f2bf(acc[i][0]) | (f2bf(acc[i][1]) << 16);
    S2[r * 64 + jg * 2 + 1] = f2bf(acc[i][2]) | (f2bf(acc[i][3]) << 16);
  }
}

// ---------------- scatter via native packed-bf16 atomics ----------------
__global__ __launch_bounds__(256) void k_scatter_down(
    const int* __restrict__ se, const int* __restrict__ re,
    const u32* __restrict__ kept,
    const u32* __restrict__ S, u32* __restrict__ A)
{
  long long id = (long long)blockIdx.x * 256 + threadIdx.x;
  int e = (int)(id >> 6), q = (int)(id & 63);
  int s = se[e], r = re[e];
  if (kept[s] & kept[r]){
    u32 ms = S[(size_t)s * 64 + q];
    u32 mr = S[(size_t)r * 64 + q];
    pk_add_bf16(&A[(size_t)r * 64 + q], ms);
    pk_add_bf16(&A[(size_t)s * 64 + q], mr);
  }
}

__global__ __launch_bounds__(256) void k_scatter_up(
    const int* __restrict__ se, const int* __restrict__ re,
    const u32* __restrict__ S, u32* __restrict__ A)
{
  long long id = (long long)blockIdx.x * 256 + threadIdx.x;
  int e = (int)(id >> 6), q = (int)(id & 63);
  int s = se[e], r = re[e];
  u32 ms = S[(size_t)s * 64 + q];
  u32 mr = S[(size_t)r * 64 + q];
  pk_add_bf16(&A[(size_t)r * 64 + q], ms);
  pk_add_bf16(&A[(size_t)s * 64 + q], mr);
}

// ---------------- fused MLP tail: gelu(agg+b1) -> @W2 gelu -> @W3 -> LN ----------------
template<int IS_DOWN>
__global__ __launch_bounds__(256) void k_mlp(
    const u32* __restrict__ A,
    const u16* __restrict__ cb1, const u16* __restrict__ cW2, const u16* __restrict__ cb2,
    const u16* __restrict__ cW3, const u16* __restrict__ cb3,
    const u16* __restrict__ cg, const u16* __restrict__ cbe,
    const u32* __restrict__ kept, const SelState* __restrict__ st,
    u32* __restrict__ Rout, void* __restrict__ fout)
{
  __shared__ float in_s[16 * 132];
  __shared__ float h_s[16 * 132];
  __shared__ u32 Wl[128 * 64];
  __shared__ float sh_mu[16], sh_rs[16];
  int t = threadIdx.x;
  int row0 = blockIdx.x * 16;

  for (int i = t; i < 16 * 64; i += 256){
    int r = i >> 6, q = i & 63;
    u32 w = A[(size_t)(row0 + r) * 64 + q];
    in_s[r * 132 + 2*q    ] = gelu_f(bflo(w) + bf2f(cb1[2*q    ]));
    in_s[r * 132 + 2*q + 1] = gelu_f(bfhi(w) + bf2f(cb1[2*q + 1]));
  }
  const u32* W2w = (const u32*)cW2;
  #pragma unroll
  for (int i = 0; i < 32; i++) Wl[t + i * 256] = W2w[t + i * 256];
  __syncthreads();

  int jg = t & 31, rg = t >> 5, j0 = jg * 4;

  { // layer 2
    const float* inb = &in_s[rg * 2 * 132];
    float acc[2][4];
    #pragma unroll
    for (int i = 0; i < 2; i++){ acc[i][0]=0.f; acc[i][1]=0.f; acc[i][2]=0.f; acc[i][3]=0.f; }
    for (int k = 0; k < 128; k++){
      u32 w0 = Wl[k * 64 + jg * 2], w1 = Wl[k * 64 + jg * 2 + 1];
      float f0=bflo(w0), f1=bfhi(w0), f2=bflo(w1), f3=bfhi(w1);
      #pragma unroll
      for (int i = 0; i < 2; i++){
        float v = inb[i * 132 + k];
        acc[i][0] += v*f0; acc[i][1] += v*f1; acc[i][2] += v*f2; acc[i][3] += v*f3;
      }
    }
    float b0 = bf2f(cb2[j0]), b1 = bf2f(cb2[j0+1]), b2 = bf2f(cb2[j0+2]), b3 = bf2f(cb2[j0+3]);
    #pragma unroll
    for (int i = 0; i < 2; i++){
      float* hp = &h_s[(rg * 2 + i) * 132 + j0];
      hp[0] = gelu_f(acc[i][0] + b0); hp[1] = gelu_f(acc[i][1] + b1);
      hp[2] = gelu_f(acc[i][2] + b2); hp[3] = gelu_f(acc[i][3] + b3);
    }
  }
  __syncthreads();
  const u32* W3w = (const u32*)cW3;
  #pragma unroll
  for (int i = 0; i < 32; i++) Wl[t + i * 256] = W3w[t + i * 256];
  __syncthreads();

  { // layer 3 -> in_s
    const float* inb = &h_s[rg * 2 * 132];
    float acc[2][4];
    #pragma unroll
    for (int i = 0; i < 2; i++){ acc[i][0]=0.f; acc[i][1]=0.f; acc[i][2]=0.f; acc[i][3]=0.f; }
    for (int k = 0; k < 128; k++){
      u32 w0 = Wl[k * 64 + jg * 2], w1 = Wl[k * 64 + jg * 2 + 1];
      float f0=bflo(w0), f1=bfhi(w0), f2=bflo(w1), f3=bfhi(w1);
      #pragma unroll
      for (int i = 0; i < 2; i++){
        float v = inb[i * 132 + k];
        acc[i][0] += v*f0; acc[i][1] += v*f1; acc[i][2] += v*f2; acc[i][3] += v*f3;
      }
    }
    float b0 = bf2f(cb3[j0]), b1 = bf2f(cb3[j0+1]), b2 = bf2f(cb3[j0+2]), b3 = bf2f(cb3[j0+3]);
    #pragma unroll
    for (int i = 0; i < 2; i++){
      float* hp = &in_s[(rg * 2 + i) * 132 + j0];
      hp[0] = acc[i][0] + b0; hp[1] = acc[i][1] + b1;
      hp[2] = acc[i][2] + b2; hp[3] = acc[i][3] + b3;
    }
  }
  __syncthreads();

  if (t < 128){ // LN stats: 8 threads per row, 16 rows
    int r = t >> 3, c0 = (t & 7) * 16;
    float s1 = 0.f, s2 = 0.f;
    #pragma unroll
    for (int i = 0; i < 16; i++){
      float v = in_s[r * 132 + c0 + i];
      s1 += v; s2 += v * v;
    }
    for (int o = 4; o > 0; o >>= 1){
      s1 += __shfl_down(s1, o, 8);
      s2 += __shfl_down(s2, o, 8);
    }
    if ((t & 7) == 0){
      float mu = s1 * 0.0078125f;
      float var = s2 * 0.0078125f - mu * mu;
      sh_mu[r] = mu;
      sh_rs[r] = rsqrtf(var + LN_EPS);
    }
  }
  __syncthreads();

  if (IS_DOWN){
    for (int i = t; i < 16 * 64; i += 256){
      int r = i >> 6, q = i & 63;
      int n = row0 + r;
      u32 outw = 0;
      if (kept[n]){
        float mu = sh_mu[r], rs = sh_rs[r];
        float v0 = (in_s[r*132 + 2*q    ] - mu) * rs * bf2f(cg[2*q    ]) + bf2f(cbe[2*q    ]);
        float v1 = (in_s[r*132 + 2*q + 1] - mu) * rs * bf2f(cg[2*q + 1]) + bf2f(cbe[2*q + 1]);
        outw = f2bf(v0) | (f2bf(v1) << 16);
      }
      Rout[(size_t)n * 64 + q] = outw;
    }
  } else {
    int isf = st->is_f32;
    for (int i = t; i < 16 * 64; i += 256){
      int r = i >> 6, q = i & 63;
      int n = row0 + r;
      float mu = sh_mu[r], rs = sh_rs[r];
      float v0 = (in_s[r*132 + 2*q    ] - mu) * rs * bf2f(cg[2*q    ]) + bf2f(cbe[2*q    ]);
      float v1 = (in_s[r*132 + 2*q + 1] - mu) * rs * bf2f(cg[2*q + 1]) + bf2f(cbe[2*q + 1]);
      if (isf){
        float2 v; v.x = v0; v.y = v1;
        *(float2*)((float*)fout + (size_t)n * 128 + 2*q) = v;
      } else {
        ((u32*)fout)[(size_t)n * 64 + q] = f2bf(v0) | (f2bf(v1) << 16);
      }
    }
  }
}

// ---------------- host launch ----------------

extern "C" void kernel_launch(void* const* d_in, const int* in_sizes, int n_in,
                              void* d_out, int out_size, void* d_ws, size_t ws_size,
                              hipStream_t stream)
{
  const void* x     = d_in[0];
  const int* eidx   = (const int*)d_in[1];
  const void* poolp = d_in[2];
  const int* senders = eidx;
  const int* receivers = eidx + N_EDGES;

  char* ws = (char*)d_ws;
  SelState* st = (SelState*)(ws + ST_OFF);
  u16*  canon  = (u16*) (ws + CANON_OFF);
  u32*  partial= (u32*) (ws + PART_OFF);
  u64*  keys   = (u64*) (ws + KEYS_OFF);
  float* tval  = (float*)(ws + TVAL_OFF);
  u32*  kept   = (u32*) (ws + KEPT_OFF);
  u32*  A      = (u32*) (ws + A_OFF);    // N x 64 bf16-pair accumulator
  u32*  S      = (u32*) d_out;           // bf16 staging; final output overwrites

  P16 ps;
  for (int i = 0; i < 16; i++) ps.q[i] = d_in[3 + i];

  k_detect<<<1, 256, 0, stream>>>((const u32*)x, st);
  k_init<<<1, 64, 0, stream>>>(st);
  k_canon<<<(C_TOT + 255) / 256, 256, 0, stream>>>(ps, st, canon);
  k_pnorm<<<1, 128, 0, stream>>>(poolp, st);
  k_score<<<N_NODES / 4, 256, 0, stream>>>(x, poolp, st, keys, tval);
  for (int pass = 0; pass < 4; pass++){
    k_histp<<<256, 256, 0, stream>>>(keys, st, partial, pass);
    k_scanp<<<1, 256, 0, stream>>>(partial, st);
  }
  k_mark<<<N_NODES / 256, 256, 0, stream>>>(keys, st, kept);
  k_tie<<<1, 256, 0, stream>>>(st, kept);

  // ---- down conv ----
  k_proj_down<<<N_NODES / 64, 256, 0, stream>>>(x, tval, canon + C_DW1, st, S);
  hipMemsetAsync(A, 0, (size_t)N_NODES * 64 * 4, stream);
  k_scatter_down<<<(int)((size_t)N_EDGES * 64 / 256), 256, 0, stream>>>(senders, receivers, kept, S, A);
  k_mlp<1><<<N_NODES / 16, 256, 0, stream>>>(A, canon + C_DB1, canon + C_DW2, canon + C_DB2,
      canon + C_DW3, canon + C_DB3, canon + C_DG, canon + C_DBE, kept, st, S, nullptr);

  // ---- up conv ----
  k_proj_up<<<N_NODES / 64, 256, 0, stream>>>(S, x, canon + C_UW1, st, S);
  hipMemsetAsync(A, 0, (size_t)N_NODES * 64 * 4, stream);
  k_scatter_up<<<(int)((size_t)N_EDGES * 64 / 256), 256, 0, stream>>>(senders, receivers, S, A);
  k_mlp<0><<<N_NODES / 16, 256, 0, stream>>>(A, canon + C_UB1, canon + C_UW2, canon + C_UB2,
      canon + C_UW3, canon + C_UB3, canon + C_UG, canon + C_UBE, kept, st, nullptr, d_out);
}

// Round 6
// 743.319 us; speedup vs baseline: 2.8841x; 1.5444x over previous
//
#include <hip/hip_runtime.h>

#define N_NODES 131072
#define N_EDGES 524288
#define K_TOP   65536
#define LN_EPS  1e-5f

typedef unsigned int u32;
typedef unsigned short u16;
typedef unsigned long long u64;

typedef __attribute__((ext_vector_type(8))) short bf8;
typedef __attribute__((ext_vector_type(4))) float f4;

// ---- ws layout ----
#define ST_OFF    0             // SelState (~52KB, reserve 64KB)
#define CANON_OFF (64u<<10)     // canon + transposed weights (~451KB) -> [64K, 576K)
#define PART_OFF  (576u<<10)    // 256x256 u32 partial hists = 256KB -> [576K, 832K)
#define KEYS_OFF  (1u<<20)      // N u64 = 1MB
#define TVAL_OFF  (2u<<20)      // N f32 = 512KB
#define KEPT_OFF  ((2u<<20)+(512u<<10)) // N u32 = 512KB
#define A_OFF     (3u<<20)      // N x 64 u32 (bf16-pair accumulator) = 32MB

// canonical parameter block offsets (bf16 elements)
#define C_DW1 0
#define C_DB1 16384
#define C_DW2 16512
#define C_DB2 32896
#define C_DW3 33024
#define C_DB3 49408
#define C_DG  49536
#define C_DBE 49664
#define C_UW1 49792
#define C_UB1 82560
#define C_UW2 82688
#define C_UB2 99072
#define C_UW3 99200
#define C_UB3 115584
#define C_UG  115712
#define C_UBE 115840
#define C_TOT 115968
// transposed weights WT[n][k] appended
#define CT_DW1 115968
#define CT_DW2 132352
#define CT_DW3 148736
#define CT_UW1 165120   /* [128][256] */
#define CT_UW2 197888
#define CT_UW3 214272
#define CT_TOT 230656
#define T_REGION (CT_TOT - CT_DW1)   /* 114688 */

__device__ __forceinline__ float bflo(u32 u){ return __uint_as_float(u << 16); }
__device__ __forceinline__ float bfhi(u32 u){ return __uint_as_float(u & 0xFFFF0000u); }
__device__ __forceinline__ float bf2f(u16 v){ return __uint_as_float(((u32)v) << 16); }
__device__ __forceinline__ u32 f2bf(float f){
  u32 u = __float_as_uint(f);
  return (u + 0x7FFFu + ((u >> 16) & 1u)) >> 16;
}
__device__ __forceinline__ float gelu_f(float x){
  return 0.5f * x * (1.0f + erff(x * 0.7071067811865476f));
}
__device__ __forceinline__ void pk_add_bf16(u32* addr, u32 val){
  asm volatile("global_atomic_pk_add_bf16 %0, %1, off"
               :: "v"(addr), "v"(val) : "memory");
}

// wave-level 16x128 GEMM step over K=128: in_s rows [m0..m0+16), WT rows = out cols.
// A frag: A[m=lane&15][k=quad*8+j]; B frag: WT[n=lane&15][k] (m97 gemm_bt pattern).
__device__ __forceinline__ void wave_gemm(const u16* in_s, const u16* w_s,
                                          int m0, int mn, int quad, f4 acc[8]){
  #pragma unroll
  for (int s = 0; s < 4; s++){
    bf8 a = *(const bf8*)(in_s + (m0 + mn) * 136 + s * 32 + quad * 8);
    #pragma unroll
    for (int j = 0; j < 8; j++){
      bf8 b = *(const bf8*)(w_s + (j * 16 + mn) * 136 + s * 32 + quad * 8);
      acc[j] = __builtin_amdgcn_mfma_f32_16x16x32_bf16(a, b, acc[j], 0, 0, 0);
    }
  }
}

struct SelState {
  u64 prefix;
  u32 krem, eqcnt;
  int is_f32;
  u32 pad;
  double inv_norm;
  u32 eqlist[4096];
  u64 eqkey[4096];
};

struct P16 { const void* q[16]; };

// ---------------- dtype detection ----------------
__global__ void k_detect(const u32* __restrict__ xw, SelState* st){
  int t = threadIdx.x;
  int cnt = 0;
  for (int i = t; i < 4096; i += 256){
    u32 w = xw[(size_t)i * 2048];
    u32 e = (w >> 23) & 0xFFu;
    if (e >= 97u && e <= 135u) cnt++;
  }
  __shared__ int sh[256];
  sh[t] = cnt; __syncthreads();
  for (int o = 128; o > 0; o >>= 1){ if (t < o) sh[t] += sh[t+o]; __syncthreads(); }
  if (t == 0) st->is_f32 = (sh[0] >= 3072) ? 1 : 0;
}

__global__ void k_init(SelState* st){
  if (threadIdx.x == 0){ st->prefix = 0; st->krem = K_TOP; st->eqcnt = 0; }
}

__global__ void k_canon(P16 ps, const SelState* __restrict__ st, u16* __restrict__ canon){
  const int off[17] = {C_DW1,C_DB1,C_DW2,C_DB2,C_DW3,C_DB3,C_DG,C_DBE,
                       C_UW1,C_UB1,C_UW2,C_UB2,C_UW3,C_UB3,C_UG,C_UBE,C_TOT};
  int i = blockIdx.x * 256 + threadIdx.x;
  if (i >= C_TOT) return;
  int seg = 0;
  #pragma unroll
  for (int s2 = 0; s2 < 16; s2++) if (i >= off[s2+1]) seg = s2 + 1;
  int j = i - off[seg];
  if (st->is_f32) canon[i] = (u16)f2bf(((const float*)ps.q[seg])[j]);
  else            canon[i] = ((const u16*)ps.q[seg])[j];
}

// build transposed weights WT[n][k] from canon W[k][n] (N==128 for all)
__global__ void k_canon_t(u16* __restrict__ canon){
  const int src[6] = {C_DW1, C_DW2, C_DW3, C_UW1, C_UW2, C_UW3};
  const int dst[7] = {CT_DW1, CT_DW2, CT_DW3, CT_UW1, CT_UW2, CT_UW3, CT_TOT};
  int i = blockIdx.x * 256 + threadIdx.x;
  if (i >= T_REGION) return;
  int g = CT_DW1 + i;
  int seg = 0;
  #pragma unroll
  for (int s2 = 0; s2 < 6; s2++) if (g >= dst[s2+1]) seg = s2 + 1;
  int loc = g - dst[seg];
  int K = (seg == 3) ? 256 : 128;
  int n = loc / K, k = loc % K;
  canon[g] = canon[src[seg] + k * 128 + n];
}

__global__ void k_pnorm(const void* __restrict__ p, SelState* st){
  int t = threadIdx.x;
  float pv = st->is_f32 ? ((const float*)p)[t] : bf2f(((const u16*)p)[t]);
  __shared__ double sh[128];
  sh[t] = (double)pv * (double)pv;
  __syncthreads();
  for (int o = 64; o > 0; o >>= 1){ if (t < o) sh[t] += sh[t+o]; __syncthreads(); }
  if (t == 0) st->inv_norm = 1.0 / sqrt(sh[0]);
}

__global__ __launch_bounds__(256) void k_score(const void* __restrict__ xraw, const void* __restrict__ praw,
                        const SelState* __restrict__ st,
                        u64* __restrict__ keys, float* __restrict__ tval){
  int t = threadIdx.x, lane = t & 63, w = t >> 6;
  int n = blockIdx.x * 4 + w;
  double d;
  if (st->is_f32){
    const float* xf = (const float*)xraw + (size_t)n * 128;
    const float* pf = (const float*)praw;
    d = (double)xf[lane] * (double)pf[lane]
      + (double)xf[64 + lane] * (double)pf[64 + lane];
  } else {
    const u32* xw = (const u32*)xraw + (size_t)n * 64;
    const u32* pw = (const u32*)praw;
    u32 xx = xw[lane], pv = pw[lane];
    d = (double)bflo(xx) * (double)bflo(pv) + (double)bfhi(xx) * (double)bfhi(pv);
  }
  for (int o = 32; o > 0; o >>= 1) d += __shfl_down(d, o, 64);
  if (lane == 0){
    double sc = d * st->inv_norm;
    u64 u = (u64)__double_as_longlong(sc);
    u64 key = (u & 0x8000000000000000ULL) ? ~u : (u | 0x8000000000000000ULL);
    keys[n] = key;
    tval[n] = tanhf((float)sc);
  }
}

// ---------------- contention-free 4-pass radix select (top 32 bits) ----------------
__global__ __launch_bounds__(256) void k_histp(const u64* __restrict__ keys,
                                               const SelState* __restrict__ st,
                                               u32* __restrict__ partial, int pass){
  __shared__ u32 h[256];
  int t = threadIdx.x;
  h[t] = 0;
  __syncthreads();
  u64 pref = st->prefix;
  int sh_d = 56 - 8 * pass;
  for (int n = blockIdx.x * 256 + t; n < N_NODES; n += 256 * 256){
    u64 k = keys[n];
    bool m = (pass == 0) ? true : ((k >> (sh_d + 8)) == pref);
    if (m) atomicAdd(&h[(u32)((k >> sh_d) & 255)], 1u);
  }
  __syncthreads();
  partial[blockIdx.x * 256 + t] = h[t];
}

__global__ void k_scanp(const u32* __restrict__ partial, SelState* st){
  __shared__ u32 tot[256];
  int t = threadIdx.x;
  u32 s = 0;
  for (int b = 0; b < 256; b++) s += partial[b * 256 + t];
  tot[t] = s;
  __syncthreads();
  if (t == 0){
    u32 target = st->krem;
    u32 cum = 0; int chosen = 255;
    for (int b = 255; b >= 0; b--){
      if (cum + tot[b] >= target){ chosen = b; break; }
      cum += tot[b];
    }
    st->prefix = (st->prefix << 8) | (u64)(u32)chosen;
    st->krem = target - cum;
  }
}

__global__ void k_mark(const u64* __restrict__ keys, SelState* st, u32* __restrict__ kept){
  int n = blockIdx.x * blockDim.x + threadIdx.x;
  u64 k = keys[n];
  u32 t32 = (u32)(k >> 32);
  u32 T = (u32)st->prefix;
  kept[n] = (t32 > T) ? 1u : 0u;
  if (t32 == T){
    u32 i = atomicAdd(&st->eqcnt, 1u);
    if (i < 4096){ st->eqlist[i] = (u32)n; st->eqkey[i] = k; }
  }
}

__global__ void k_tie(SelState* st, u32* __restrict__ kept){
  u32 m = st->eqcnt; if (m > 4096) m = 4096;
  u32 r = st->krem;
  for (u32 i = threadIdx.x; i < m; i += blockDim.x){
    u64 ki = st->eqkey[i]; u32 ii = st->eqlist[i];
    u32 rank = 0;
    for (u32 j = 0; j < m; j++){
      u64 kj = st->eqkey[j];
      rank += (kj > ki || (kj == ki && st->eqlist[j] < ii)) ? 1u : 0u;
    }
    if (rank < r) kept[ii] = 1u;
  }
}

// ---------------- MFMA projection GEMMs ----------------
// S[n] = bf16(x[n]*tval[n] @ dW1)
__global__ __launch_bounds__(256) void k_proj_down(
    const void* __restrict__ xraw, const float* __restrict__ tval,
    const u16* __restrict__ W1T, const SelState* __restrict__ st,
    u32* __restrict__ S)
{
  __shared__ u16 in_s[64 * 136];
  __shared__ u16 w_s[128 * 136];
  int t = threadIdx.x;
  int lane = t & 63, wv = t >> 6;
  int row0 = blockIdx.x * 64;

  if (st->is_f32){
    const float* xf = (const float*)xraw + (size_t)row0 * 128;
    for (int i = t; i < 64 * 64; i += 256){
      int r = i >> 6, q = i & 63;
      float tv = tval[row0 + r];
      float2 v = *(const float2*)(xf + (size_t)r * 128 + 2 * q);
      *(u32*)&in_s[r * 136 + 2 * q] = f2bf(v.x * tv) | (f2bf(v.y * tv) << 16);
    }
  } else {
    const u32* xw = (const u32*)xraw + (size_t)row0 * 64;
    for (int i = t; i < 64 * 64; i += 256){
      int r = i >> 6, q = i & 63;
      u32 u = xw[(size_t)r * 64 + q];
      float tv = tval[row0 + r];
      *(u32*)&in_s[r * 136 + 2 * q] = f2bf(bflo(u) * tv) | (f2bf(bfhi(u) * tv) << 16);
    }
  }
  const u32* Ww = (const u32*)W1T;
  for (int i = t; i < 128 * 64; i += 256){
    int nr = i >> 6, q = i & 63;
    *(u32*)&w_s[nr * 136 + 2 * q] = Ww[i];
  }
  __syncthreads();

  int m0 = wv * 16, mn = lane & 15, quad = lane >> 4;
  f4 acc[8];
  #pragma unroll
  for (int j = 0; j < 8; j++){ acc[j][0]=0.f; acc[j][1]=0.f; acc[j][2]=0.f; acc[j][3]=0.f; }
  wave_gemm(in_s, w_s, m0, mn, quad, acc);
  __syncthreads();

  #pragma unroll
  for (int j = 0; j < 8; j++){
    int c = j * 16 + mn;
    #pragma unroll
    for (int rg = 0; rg < 4; rg++)
      in_s[(m0 + quad * 4 + rg) * 136 + c] = (u16)f2bf(acc[j][rg]);
  }
  __syncthreads();
  for (int i = t; i < 64 * 64; i += 256){
    int r = i >> 6, q = i & 63;
    S[(size_t)(row0 + r) * 64 + q] = *(u32*)&in_s[r * 136 + 2 * q];
  }
}

// S2[n] = bf16(R[n] @ uW1[0:128,:] + x[n] @ uW1[128:256,:]) (in-place on d_out rows)
__global__ __launch_bounds__(256) void k_proj_up(
    const u32* __restrict__ R, const void* __restrict__ xraw,
    const u16* __restrict__ W1T, const SelState* __restrict__ st,
    u32* __restrict__ S2)
{
  __shared__ u16 in_s[64 * 136];
  __shared__ u16 w_s[128 * 136];
  int t = threadIdx.x;
  int lane = t & 63, wv = t >> 6;
  int row0 = blockIdx.x * 64;
  int m0 = wv * 16, mn = lane & 15, quad = lane >> 4;

  f4 acc[8];
  #pragma unroll
  for (int j = 0; j < 8; j++){ acc[j][0]=0.f; acc[j][1]=0.f; acc[j][2]=0.f; acc[j][3]=0.f; }

  for (int ph = 0; ph < 2; ph++){
    if (ph == 0){
      for (int i = t; i < 64 * 64; i += 256){
        int r = i >> 6, q = i & 63;
        *(u32*)&in_s[r * 136 + 2 * q] = R[(size_t)(row0 + r) * 64 + q];
      }
    } else if (st->is_f32){
      const float* xf = (const float*)xraw + (size_t)row0 * 128;
      for (int i = t; i < 64 * 64; i += 256){
        int r = i >> 6, q = i & 63;
        float2 v = *(const float2*)(xf + (size_t)r * 128 + 2 * q);
        *(u32*)&in_s[r * 136 + 2 * q] = f2bf(v.x) | (f2bf(v.y) << 16);
      }
    } else {
      const u32* xw = (const u32*)xraw + (size_t)row0 * 64;
      for (int i = t; i < 64 * 64; i += 256){
        int r = i >> 6, q = i & 63;
        *(u32*)&in_s[r * 136 + 2 * q] = xw[(size_t)r * 64 + q];
      }
    }
    // WT slice: rows n=0..127, k = ph*128 .. ph*128+127 from [128][256]
    const u32* Ww = (const u32*)W1T;
    for (int i = t; i < 128 * 64; i += 256){
      int nr = i >> 6, q = i & 63;
      *(u32*)&w_s[nr * 136 + 2 * q] = Ww[nr * 128 + ph * 64 + q];
    }
    __syncthreads();
    wave_gemm(in_s, w_s, m0, mn, quad, acc);
    __syncthreads();
  }

  #pragma unroll
  for (int j = 0; j < 8; j++){
    int c = j * 16 + mn;
    #pragma unroll
    for (int rg = 0; rg < 4; rg++)
      in_s[(m0 + quad * 4 + rg) * 136 + c] = (u16)f2bf(acc[j][rg]);
  }
  __syncthreads();
  for (int i = t; i < 64 * 64; i += 256){
    int r = i >> 6, q = i & 63;
    S2[(size_t)(row0 + r) * 64 + q] = *(u32*)&in_s[r * 136 + 2 * q];
  }
}

// ---------------- scatter via native packed-bf16 atomics ----------------
__global__ __launch_bounds__(256) void k_scatter_down(
    const int* __restrict__ se, const int* __restrict__ re,
    const u32* __restrict__ kept,
    const u32* __restrict__ S, u32* __restrict__ A)
{
  long long id = (long long)blockIdx.x * 256 + threadIdx.x;
  int e = (int)(id >> 6), q = (int)(id & 63);
  int s = se[e], r = re[e];
  if (kept[s] & kept[r]){
    u32 ms = S[(size_t)s * 64 + q];
    u32 mr = S[(size_t)r * 64 + q];
    pk_add_bf16(&A[(size_t)r * 64 + q], ms);
    pk_add_bf16(&A[(size_t)s * 64 + q], mr);
  }
}

__global__ __launch_bounds__(256) void k_scatter_up(
    const int* __restrict__ se, const int* __restrict__ re,
    const u32* __restrict__ S, u32* __restrict__ A)
{
  long long id = (long long)blockIdx.x * 256 + threadIdx.x;
  int e = (int)(id >> 6), q = (int)(id & 63);
  int s = se[e], r = re[e];
  u32 ms = S[(size_t)s * 64 + q];
  u32 mr = S[(size_t)r * 64 + q];
  pk_add_bf16(&A[(size_t)r * 64 + q], ms);
  pk_add_bf16(&A[(size_t)s * 64 + q], mr);
}

// ---------------- fused MFMA MLP tail: gelu(agg+b1) -> @W2 gelu -> @W3 -> LN ----------------
template<int IS_DOWN>
__global__ __launch_bounds__(256) void k_mlp(
    const u32* __restrict__ A,
    const u16* __restrict__ cb1, const u16* __restrict__ cW2T, const u16* __restrict__ cb2,
    const u16* __restrict__ cW3T, const u16* __restrict__ cb3,
    const u16* __restrict__ cg, const u16* __restrict__ cbe,
    const u32* __restrict__ kept, const SelState* __restrict__ st,
    u32* __restrict__ Rout, void* __restrict__ fout)
{
  __shared__ u16 in_s[64 * 136];
  __shared__ u16 w_s[128 * 136];   // reused as f32 out buffer [64][132]
  __shared__ float sh_mu[64], sh_rs[64];
  int t = threadIdx.x;
  int lane = t & 63, wv = t >> 6;
  int row0 = blockIdx.x * 64;
  int m0 = wv * 16, mn = lane & 15, quad = lane >> 4;

  // stage h1 = gelu(agg + b1) as bf16, and W2T
  for (int i = t; i < 64 * 64; i += 256){
    int r = i >> 6, q = i & 63;
    u32 w = A[(size_t)(row0 + r) * 64 + q];
    float v0 = gelu_f(bflo(w) + bf2f(cb1[2*q]));
    float v1 = gelu_f(bfhi(w) + bf2f(cb1[2*q+1]));
    *(u32*)&in_s[r * 136 + 2 * q] = f2bf(v0) | (f2bf(v1) << 16);
  }
  const u32* W2w = (const u32*)cW2T;
  for (int i = t; i < 128 * 64; i += 256){
    int nr = i >> 6, q = i & 63;
    *(u32*)&w_s[nr * 136 + 2 * q] = W2w[i];
  }
  __syncthreads();

  f4 acc[8];
  #pragma unroll
  for (int j = 0; j < 8; j++){ acc[j][0]=0.f; acc[j][1]=0.f; acc[j][2]=0.f; acc[j][3]=0.f; }
  wave_gemm(in_s, w_s, m0, mn, quad, acc);
  __syncthreads();   // everyone done reading in_s / w_s

  // h2 = gelu(acc + b2) -> in_s (own rows), restage W3T
  #pragma unroll
  for (int j = 0; j < 8; j++){
    int c = j * 16 + mn;
    float bb = bf2f(cb2[c]);
    #pragma unroll
    for (int rg = 0; rg < 4; rg++)
      in_s[(m0 + quad * 4 + rg) * 136 + c] = (u16)f2bf(gelu_f(acc[j][rg] + bb));
  }
  const u32* W3w = (const u32*)cW3T;
  for (int i = t; i < 128 * 64; i += 256){
    int nr = i >> 6, q = i & 63;
    *(u32*)&w_s[nr * 136 + 2 * q] = W3w[i];
  }
  __syncthreads();

  #pragma unroll
  for (int j = 0; j < 8; j++){ acc[j][0]=0.f; acc[j][1]=0.f; acc[j][2]=0.f; acc[j][3]=0.f; }
  wave_gemm(in_s, w_s, m0, mn, quad, acc);
  __syncthreads();   // done reading w_s; safe to reuse as f32 buffer

  float* fbuf = (float*)w_s;
  #pragma unroll
  for (int j = 0; j < 8; j++){
    int c = j * 16 + mn;
    float bb = bf2f(cb3[c]);
    #pragma unroll
    for (int rg = 0; rg < 4; rg++)
      fbuf[(m0 + quad * 4 + rg) * 132 + c] = acc[j][rg] + bb;
  }
  __syncthreads();

  { // LN stats: 4 threads per row, 64 rows
    int r = t >> 2, c0 = (t & 3) * 32;
    float s1 = 0.f, s2 = 0.f;
    #pragma unroll
    for (int i = 0; i < 32; i++){
      float v = fbuf[r * 132 + c0 + i];
      s1 += v; s2 += v * v;
    }
    s1 += __shfl_down(s1, 2, 4); s2 += __shfl_down(s2, 2, 4);
    s1 += __shfl_down(s1, 1, 4); s2 += __shfl_down(s2, 1, 4);
    if ((t & 3) == 0){
      float mu = s1 * 0.0078125f;
      float var = s2 * 0.0078125f - mu * mu;
      sh_mu[r] = mu;
      sh_rs[r] = rsqrtf(var + LN_EPS);
    }
  }
  __syncthreads();

  if (IS_DOWN){
    for (int i = t; i < 64 * 64; i += 256){
      int r = i >> 6, q = i & 63;
      int n = row0 + r;
      u32 outw = 0;
      if (kept[n]){
        float mu = sh_mu[r], rs = sh_rs[r];
        float v0 = (fbuf[r*132 + 2*q    ] - mu) * rs * bf2f(cg[2*q    ]) + bf2f(cbe[2*q    ]);
        float v1 = (fbuf[r*132 + 2*q + 1] - mu) * rs * bf2f(cg[2*q + 1]) + bf2f(cbe[2*q + 1]);
        outw = f2bf(v0) | (f2bf(v1) << 16);
      }
      Rout[(size_t)n * 64 + q] = outw;
    }
  } else {
    int isf = st->is_f32;
    for (int i = t; i < 64 * 64; i += 256){
      int r = i >> 6, q = i & 63;
      int n = row0 + r;
      float mu = sh_mu[r], rs = sh_rs[r];
      float v0 = (fbuf[r*132 + 2*q    ] - mu) * rs * bf2f(cg[2*q    ]) + bf2f(cbe[2*q    ]);
      float v1 = (fbuf[r*132 + 2*q + 1] - mu) * rs * bf2f(cg[2*q + 1]) + bf2f(cbe[2*q + 1]);
      if (isf){
        float2 v; v.x = v0; v.y = v1;
        *(float2*)((float*)fout + (size_t)n * 128 + 2*q) = v;
      } else {
        ((u32*)fout)[(size_t)n * 64 + q] = f2bf(v0) | (f2bf(v1) << 16);
      }
    }
  }
}

// ---------------- host launch ----------------

extern "C" void kernel_launch(void* const* d_in, const int* in_sizes, int n_in,
                              void* d_out, int out_size, void* d_ws, size_t ws_size,
                              hipStream_t stream)
{
  const void* x     = d_in[0];
  const int* eidx   = (const int*)d_in[1];
  const void* poolp = d_in[2];
  const int* senders = eidx;
  const int* receivers = eidx + N_EDGES;

  char* ws = (char*)d_ws;
  SelState* st = (SelState*)(ws + ST_OFF);
  u16*  canon  = (u16*) (ws + CANON_OFF);
  u32*  partial= (u32*) (ws + PART_OFF);
  u64*  keys   = (u64*) (ws + KEYS_OFF);
  float* tval  = (float*)(ws + TVAL_OFF);
  u32*  kept   = (u32*) (ws + KEPT_OFF);
  u32*  A      = (u32*) (ws + A_OFF);
  u32*  S      = (u32*) d_out;

  P16 ps;
  for (int i = 0; i < 16; i++) ps.q[i] = d_in[3 + i];

  k_detect<<<1, 256, 0, stream>>>((const u32*)x, st);
  k_init<<<1, 64, 0, stream>>>(st);
  k_canon<<<(C_TOT + 255) / 256, 256, 0, stream>>>(ps, st, canon);
  k_canon_t<<<(T_REGION + 255) / 256, 256, 0, stream>>>(canon);
  k_pnorm<<<1, 128, 0, stream>>>(poolp, st);
  k_score<<<N_NODES / 4, 256, 0, stream>>>(x, poolp, st, keys, tval);
  for (int pass = 0; pass < 4; pass++){
    k_histp<<<256, 256, 0, stream>>>(keys, st, partial, pass);
    k_scanp<<<1, 256, 0, stream>>>(partial, st);
  }
  k_mark<<<N_NODES / 256, 256, 0, stream>>>(keys, st, kept);
  k_tie<<<1, 256, 0, stream>>>(st, kept);

  // ---- down conv ----
  k_proj_down<<<N_NODES / 64, 256, 0, stream>>>(x, tval, canon + CT_DW1, st, S);
  hipMemsetAsync(A, 0, (size_t)N_NODES * 64 * 4, stream);
  k_scatter_down<<<(int)((size_t)N_EDGES * 64 / 256), 256, 0, stream>>>(senders, receivers, kept, S, A);
  k_mlp<1><<<N_NODES / 64, 256, 0, stream>>>(A, canon + C_DB1, canon + CT_DW2, canon + C_DB2,
      canon + CT_DW3, canon + C_DB3, canon + C_DG, canon + C_DBE, kept, st, S, nullptr);

  // ---- up conv ----
  k_proj_up<<<N_NODES / 64, 256, 0, stream>>>(S, x, canon + CT_UW1, st, S);
  hipMemsetAsync(A, 0, (size_t)N_NODES * 64 * 4, stream);
  k_scatter_up<<<(int)((size_t)N_EDGES * 64 / 256), 256, 0, stream>>>(senders, receivers, S, A);
  k_mlp<0><<<N_NODES / 64, 256, 0, stream>>>(A, canon + C_UB1, canon + CT_UW2, canon + C_UB2,
      canon + CT_UW3, canon + C_UB3, canon + C_UG, canon + C_UBE, kept, st, nullptr, d_out);
}